// Round 1
// baseline (41385.403 us; speedup 1.0000x reference)
//
#include <hip/hip_runtime.h>
#include <hip/hip_cooperative_groups.h>

namespace cg = cooperative_groups;

typedef unsigned short u16;
typedef __attribute__((ext_vector_type(8))) short short8;   // 8 x bf16
typedef __attribute__((ext_vector_type(4))) float float4v;  // MFMA acc

// ---- output offsets (floats) ----
#define O_MEANS 0
#define O_LS    1310720
#define O_RHO   2621440
#define O_PI    3276800
#define O_EOS   3932160
#define O_H0H   3964928
#define O_H0C   3990528
#define O_H1H   4016128
#define O_H1C   4041728
#define O_H2H   4067328
#define O_H2C   4092928
#define O_PW    4118528
#define O_PK    4122368
#define O_AL    4123008

struct P {
  const float *strokes; const int *text; const int *tlen;
  const float *h0h,*h0c,*h1h,*h1c,*h2h,*h2c,*pw,*pk;
  const float *bih0,*bhh0,*bih1,*bhh1,*bih2,*bhh2;
  const float *Wwin,*bwin;
  const float *bmu,*bls,*brho,*bpi,*beos;
  u16 *B0,*B1,*B2,*BP;          // fragment-packed weights
  u16 *A0,*A1,*A2;              // fragment-packed activations per step
  u16 *y0,*y1,*y2;              // bf16 row-major hidden histories [T][64][400]
  float *c0,*c1,*c2,*kws;       // fp32 cell states + attention kappa
  float *out;
};

__device__ __forceinline__ u16 f2bf(float f){
  unsigned int x = __float_as_uint(f);
  unsigned int r = x + 0x7FFFu + ((x >> 16) & 1u);
  return (u16)(r >> 16);
}
__device__ __forceinline__ float bf2f(u16 u){
  return __uint_as_float(((unsigned int)u) << 16);
}
// A-pack element (t, batch b, k) for a layer with KB k-blocks.
// block = (t*4 + b/16)*KB + k/32 ; inside block: lane=(k>>3&3)*16+(b&15), elem k&7
__device__ __forceinline__ size_t aidx(int t, int b, int k, int KB){
  return ((size_t)((t*4 + (b>>4))*KB + (k>>5)))*512
       + (size_t)(((((k>>3)&3)*16) + (b&15))*8 + (k&7));
}
__device__ __forceinline__ float sigm(float x){ return 1.f/(1.f+__expf(-x)); }
__device__ __forceinline__ float tanh_f(float x){ return 2.f/(1.f+__expf(-2.f*x)) - 1.f; }

// ---------------- weight packing ----------------
// B-fragment order: lane holds B[k=(lane>>4)*8+j][n=lane&15]; gate permutation:
// slice s, col c -> gate g = (c>>2)*400 + 4*s + (c&3)  (i,f,g,o interleave)
__global__ void kpackB(const float* __restrict__ Wih, const float* __restrict__ Whh,
                       u16* __restrict__ dst, int KB, int kih, int total){
  int tid = blockIdx.x*256 + threadIdx.x;
  if (tid >= total) return;
  int e = tid & 511, blk = tid >> 9;
  int lane = e >> 3, j = e & 7;
  int s = blk / KB, kb = blk % KB;
  int q = lane >> 4, n = lane & 15;
  int k = kb*32 + q*8 + j;
  int g = (n>>2)*400 + s*4 + (n&3);
  float v = 0.f;
  if (k < kih) v = Wih[(size_t)g*kih + k];
  else if (k < kih + 400) v = Whh[(size_t)g*400 + (k - kih)];
  dst[tid] = f2bf(v);
}

// projection weights: cols 0..39 mu, 40..79 ls, 80..99 rho, 100..119 pi, 120 eos
__global__ void kpackBP(const float* __restrict__ Wmu, const float* __restrict__ Wls,
                        const float* __restrict__ Wrho, const float* __restrict__ Wpi,
                        const float* __restrict__ Weos, u16* __restrict__ dst){
  int tid = blockIdx.x*256 + threadIdx.x;
  if (tid >= 8*38*512) return;
  int e = tid & 511, blk = tid >> 9;
  int lane = e >> 3, j = e & 7;
  int ns = blk / 38, kb = blk % 38;
  int q = lane >> 4, n = lane & 15;
  int k = kb*32 + q*8 + j;
  int col = ns*16 + n;
  float v = 0.f;
  if (k < 1200){
    if (col < 40)       v = Wmu[(size_t)col*1200 + k];
    else if (col < 80)  v = Wls[(size_t)(col-40)*1200 + k];
    else if (col < 100) v = Wrho[(size_t)(col-80)*1200 + k];
    else if (col < 120) v = Wpi[(size_t)(col-100)*1200 + k];
    else if (col == 120) v = Weos[k];
  }
  dst[tid] = f2bf(v);
}

// strokes rows + zero pads for all t (ws is 0xAA-poisoned every run)
__global__ void kfillA(P p){
  int tid = blockIdx.x*256 + threadIdx.x;
  if (tid >= 512*64*32) return;
  int it = tid & 31; int r = tid >> 5; int b = r & 63; int t = r >> 6;
  const float* sx = p.strokes + ((size_t)t*64 + b)*3;
  if (it < 3)       p.A0[aidx(t,b,it,15)]            = f2bf(sx[it]);
  else if (it < 20) p.A0[aidx(t,b,463+(it-3),15)]    = 0;       // K pad 463..479
  else if (it < 23) p.A1[aidx(t,b,460+(it-20),27)]   = f2bf(sx[it-20]);
  else if (it == 23) p.A1[aidx(t,b,863,27)]          = 0;       // K pad 863
  else if (it < 27) p.A2[aidx(t,b,460+(it-24),27)]   = f2bf(sx[it-24]);
  else if (it == 27) p.A2[aidx(t,b,863,27)]          = 0;
}

// initial states -> packs / fp32 state buffers
__global__ void kinit(P p){
  int tid = blockIdx.x*256 + threadIdx.x;
  if (tid < 25600){ int b=tid/400, j=tid%400; p.A0[aidx(0,b,63+j,15)]  = f2bf(p.h0h[tid]); }
  else if (tid < 51200){ int i=tid-25600; p.c0[i] = p.h0c[i]; }
  else if (tid < 76800){ int i=tid-51200; int b=i/400, j=i%400; p.A1[aidx(0,b,463+j,27)] = f2bf(p.h1h[i]); }
  else if (tid < 102400){ int i=tid-76800; p.c1[i] = p.h1c[i]; }
  else if (tid < 128000){ int i=tid-102400; int b=i/400, j=i%400; p.A2[aidx(0,b,463+j,27)] = f2bf(p.h2h[i]); }
  else if (tid < 153600){ int i=tid-128000; p.c2[i] = p.h2c[i]; }
  else if (tid < 157440){ int i=tid-153600; int b=i/60, l=i%60; p.A0[aidx(0,b,3+l,15)] = f2bf(p.pw[i]); }
  else if (tid < 158080){ int i=tid-157440; p.kws[i] = p.pk[i]; }
}

// ---------------- main persistent kernel ----------------
__device__ __forceinline__ float4v gate_mma(const u16* __restrict__ Apack,
                                            const u16* __restrict__ Bpack,
                                            int KB, int t, int s, int lane, int wave){
  float4v a0 = {0.f,0.f,0.f,0.f}, a1 = {0.f,0.f,0.f,0.f};
  const u16* Ab = Apack + ((size_t)(t*4 + wave)*KB)*512 + (size_t)lane*8;
  const u16* Bb = Bpack + ((size_t)s*KB)*512 + (size_t)lane*8;
  for (int kb = 0; kb < KB; kb += 2){
    short8 af = *reinterpret_cast<const short8*>(Ab + (size_t)kb*512);
    short8 bf = *reinterpret_cast<const short8*>(Bb + (size_t)kb*512);
    a0 = __builtin_amdgcn_mfma_f32_16x16x32_bf16(af, bf, a0, 0, 0, 0);
    if (kb + 1 < KB){
      short8 af1 = *reinterpret_cast<const short8*>(Ab + (size_t)(kb+1)*512);
      short8 bf1 = *reinterpret_cast<const short8*>(Bb + (size_t)(kb+1)*512);
      a1 = __builtin_amdgcn_mfma_f32_16x16x32_bf16(af1, bf1, a1, 0, 0, 0);
    }
  }
  a0[0]+=a1[0]; a0[1]+=a1[1]; a0[2]+=a1[2]; a0[3]+=a1[3];
  return a0;
}

__global__ __launch_bounds__(256) void kmain(P p){
  cg::grid_group grd = cg::this_grid();
  const int wg = blockIdx.x, tid = threadIdx.x;
  const int lane = tid & 63, wave = tid >> 6;

  __shared__ float ldsg[64*17];
  // window-phase scratch
  __shared__ float hsh[400];
  __shared__ float po[240];
  __shared__ float osh[30];
  __shared__ float ash[10], bsh[10], ksh[10];
  __shared__ float phish[64];
  __shared__ int   txsh[64];

  // pipelined rounds: L0 at t=r, L1 at t=r-1, L2 at t=r-2; window(t=r) in phase B
  for (int r = 0; r < 514; ++r){
    // ---------- phase A: gate GEMM + LSTM pointwise, all three layers ----------
    bool run = false; int t = 0, s = 0;
    const u16 *Ap = nullptr, *Bp = nullptr; int KB = 0;
    const float *bi = nullptr, *bh = nullptr; float *cw = nullptr;
    u16 *yr = nullptr, *As = nullptr, *An = nullptr;
    int sKB = 0, sk = 0, nKB = 0, nk = 0, oh = 0, oc = 0;
    if (wg < 100){
      t = r; s = wg;
      if (t < 512){ run = true; Ap=p.A0; Bp=p.B0; KB=15; bi=p.bih0; bh=p.bhh0; cw=p.c0;
        yr=p.y0; As=p.A1; sKB=27; sk=0; An=p.A0; nKB=15; nk=63; oh=O_H0H; oc=O_H0C; }
    } else if (wg < 200){
      t = r - 1; s = wg - 100;
      if (t >= 0 && t < 512){ run = true; Ap=p.A1; Bp=p.B1; KB=27; bi=p.bih1; bh=p.bhh1; cw=p.c1;
        yr=p.y1; As=p.A2; sKB=27; sk=0; An=p.A1; nKB=27; nk=463; oh=O_H1H; oc=O_H1C; }
    } else {
      t = r - 2; s = wg - 200;
      if (t >= 0 && t < 512){ run = true; Ap=p.A2; Bp=p.B2; KB=27; bi=p.bih2; bh=p.bhh2; cw=p.c2;
        yr=p.y2; As=nullptr; An=p.A2; nKB=27; nk=463; oh=O_H2H; oc=O_H2C; }
    }
    if (run){
      float4v acc = gate_mma(Ap, Bp, KB, t, s, lane, wave);
      const int c = lane & 15;
      const int g = (c>>2)*400 + s*4 + (c&3);
      const float bias = bi[g] + bh[g];
      const int rb = wave*16 + ((lane>>4)<<2);
      #pragma unroll
      for (int rr = 0; rr < 4; ++rr) ldsg[(rb+rr)*17 + c] = acc[rr] + bias;
    }
    __syncthreads();
    if (run){
      const int b = tid >> 2, jj = tid & 3, j = s*4 + jj;
      float gi = ldsg[b*17 + jj],     gf = ldsg[b*17 + 4 + jj];
      float gg = ldsg[b*17 + 8 + jj], go = ldsg[b*17 + 12 + jj];
      float cp = cw[b*400 + j];
      float cn = sigm(gf)*cp + sigm(gi)*tanh_f(gg);
      float hh = sigm(go)*tanh_f(cn);
      cw[b*400 + j] = cn;
      u16 hb = f2bf(hh);
      yr[((size_t)t*64 + b)*400 + j] = hb;
      if (As) As[aidx(t, b, sk + j, sKB)] = hb;
      if (t < 511) An[aidx(t+1, b, nk + j, nKB)] = hb;
      else { p.out[oh + b*400 + j] = hh; p.out[oc + b*400 + j] = cn; }
    }
    grd.sync();

    // ---------- phase B: Gaussian window attention for t = r ----------
    if (wg < 64 && r < 512){
      const int b = wg, tw = r;
      for (int i = tid; i < 400; i += 256)
        hsh[i] = bf2f(p.y0[((size_t)tw*64 + b)*400 + i]);
      if (tid < 64) txsh[tid] = p.text[b*64 + tid];
      __syncthreads();
      if (tid < 240){
        int n = tid >> 3, kc = tid & 7;
        const float* wr = p.Wwin + n*400 + kc*50;
        const float* hr = hsh + kc*50;
        float sacc = 0.f;
        for (int k = 0; k < 50; ++k) sacc += hr[k]*wr[k];
        po[tid] = sacc;
      }
      __syncthreads();
      if (tid < 30){
        float sv = p.bwin[tid];
        #pragma unroll
        for (int kc = 0; kc < 8; ++kc) sv += po[tid*8 + kc];
        osh[tid] = sv;
      }
      __syncthreads();
      if (tid < 10){
        float a  = __expf(osh[tid]);
        float bb = __expf(osh[10 + tid]);
        float kn = p.kws[b*10 + tid] + 0.05f*__expf(osh[20 + tid]);
        p.kws[b*10 + tid] = kn;
        ash[tid] = a; bsh[tid] = bb; ksh[tid] = kn;
        if (tw == 511) p.out[O_PK + b*10 + tid] = kn;
      }
      __syncthreads();
      if (tid < 64){
        const int u = tid;
        float phi = 0.f;
        if (u < p.tlen[b]){
          #pragma unroll
          for (int n = 0; n < 10; ++n){
            float d = ksh[n] - (float)u;
            phi += ash[n]*__expf(-bsh[n]*d*d);
          }
        }
        phish[u] = phi;
        p.out[O_AL + ((size_t)tw*64 + b)*64 + u] = phi;
      }
      __syncthreads();
      if (tid < 60){
        const int l = tid;
        float wv = 0.f;
        for (int u = 0; u < 64; ++u) if (txsh[u] == l) wv += phish[u];
        u16 wb = f2bf(wv);
        p.A1[aidx(tw, b, 400 + l, 27)] = wb;
        p.A2[aidx(tw, b, 400 + l, 27)] = wb;
        if (tw < 511) p.A0[aidx(tw+1, b, 3 + l, 15)] = wb;
        else p.out[O_PW + b*60 + l] = wv;
      }
    }
    grd.sync();
  }
}

// ---------------- output heads ----------------
__global__ __launch_bounds__(256) void kproj(P p){
  const int t = blockIdx.x >> 3, ns = blockIdx.x & 7;
  const int tid = threadIdx.x, lane = tid & 63, wave = tid >> 6;
  const int m = lane & 15, q = lane >> 4;
  float4v acc = {0.f,0.f,0.f,0.f};
  const size_t rowA = (size_t)t*64 + wave*16 + m;
  const u16* Bb = p.BP + ((size_t)ns*38)*512 + (size_t)lane*8;
  for (int kb = 0; kb < 38; ++kb){
    int k0 = kb*32 + q*8;
    const u16* src; int off;
    if (k0 < 400){ src = p.y0; off = k0; }
    else if (k0 < 800){ src = p.y1; off = k0 - 400; }
    else if (k0 < 1200){ src = p.y2; off = k0 - 800; }
    else { src = p.y0; off = 0; }     // B rows are zero for k>=1200
    short8 af = *reinterpret_cast<const short8*>(src + rowA*400 + off);
    short8 bf = *reinterpret_cast<const short8*>(Bb + (size_t)kb*512);
    acc = __builtin_amdgcn_mfma_f32_16x16x32_bf16(af, bf, acc, 0, 0, 0);
  }
  const int j = ns*16 + (lane & 15);
  const int bo = wave*16 + q*4;
  #pragma unroll
  for (int rr = 0; rr < 4; ++rr){
    float v = acc[rr];
    size_t ro = (size_t)t*64 + bo + rr;
    if (j < 40)        p.out[O_MEANS + ro*40 + j]        = v + p.bmu[j];
    else if (j < 80)   p.out[O_LS    + ro*40 + (j-40)]   = v + p.bls[j-40];
    else if (j < 100)  p.out[O_RHO   + ro*20 + (j-80)]   = tanhf(v + p.brho[j-80]);
    else if (j < 120)  p.out[O_PI    + ro*20 + (j-100)]  = v + p.bpi[j-100];
    else if (j == 120) p.out[O_EOS   + ro]               = v + p.beos[0];
  }
}

// ---------------- host ----------------
extern "C" void kernel_launch(void* const* d_in, const int* in_sizes, int n_in,
                              void* d_out, int out_size, void* d_ws, size_t ws_size,
                              hipStream_t stream){
  P p;
  p.strokes = (const float*)d_in[0];
  p.text    = (const int*)  d_in[1];
  p.tlen    = (const int*)  d_in[2];
  p.h0h = (const float*)d_in[3];  p.h0c = (const float*)d_in[4];
  p.h1h = (const float*)d_in[5];  p.h1c = (const float*)d_in[6];
  p.h2h = (const float*)d_in[7];  p.h2c = (const float*)d_in[8];
  p.pw  = (const float*)d_in[9];  p.pk  = (const float*)d_in[10];
  const float* Wih0 = (const float*)d_in[11]; const float* Whh0 = (const float*)d_in[12];
  p.bih0 = (const float*)d_in[13]; p.bhh0 = (const float*)d_in[14];
  const float* Wih1 = (const float*)d_in[15]; const float* Whh1 = (const float*)d_in[16];
  p.bih1 = (const float*)d_in[17]; p.bhh1 = (const float*)d_in[18];
  const float* Wih2 = (const float*)d_in[19]; const float* Whh2 = (const float*)d_in[20];
  p.bih2 = (const float*)d_in[21]; p.bhh2 = (const float*)d_in[22];
  p.Wwin = (const float*)d_in[23]; p.bwin = (const float*)d_in[24];
  const float* Wmu  = (const float*)d_in[25]; p.bmu  = (const float*)d_in[26];
  const float* Wls  = (const float*)d_in[27]; p.bls  = (const float*)d_in[28];
  const float* Wrho = (const float*)d_in[29]; p.brho = (const float*)d_in[30];
  const float* Wpi  = (const float*)d_in[31]; p.bpi  = (const float*)d_in[32];
  const float* Weos = (const float*)d_in[33]; p.beos = (const float*)d_in[34];
  p.out = (float*)d_out;

  char* w = (char*)d_ws; size_t off = 0;
  auto alloc = [&](size_t bytes)->void*{ void* r = w + off; off += (bytes + 511) & ~(size_t)511; return r; };
  p.B0 = (u16*)alloc((size_t)100*15*1024);
  p.B1 = (u16*)alloc((size_t)100*27*1024);
  p.B2 = (u16*)alloc((size_t)100*27*1024);
  p.BP = (u16*)alloc((size_t)8*38*1024);
  p.A0 = (u16*)alloc((size_t)512*4*15*1024);
  p.A1 = (u16*)alloc((size_t)512*4*27*1024);
  p.A2 = (u16*)alloc((size_t)512*4*27*1024);
  p.y0 = (u16*)alloc((size_t)512*64*400*2);
  p.y1 = (u16*)alloc((size_t)512*64*400*2);
  p.y2 = (u16*)alloc((size_t)512*64*400*2);
  p.c0 = (float*)alloc((size_t)64*400*4);
  p.c1 = (float*)alloc((size_t)64*400*4);
  p.c2 = (float*)alloc((size_t)64*400*4);
  p.kws = (float*)alloc((size_t)64*10*4);
  // total ~231 MB of d_ws

  kpackB<<<dim3(3000), dim3(256), 0, stream>>>(Wih0, Whh0, p.B0, 15, 63, 100*15*512);
  kpackB<<<dim3(5400), dim3(256), 0, stream>>>(Wih1, Whh1, p.B1, 27, 463, 100*27*512);
  kpackB<<<dim3(5400), dim3(256), 0, stream>>>(Wih2, Whh2, p.B2, 27, 463, 100*27*512);
  kpackBP<<<dim3(608), dim3(256), 0, stream>>>(Wmu, Wls, Wrho, Wpi, Weos, p.BP);
  kfillA<<<dim3(4096), dim3(256), 0, stream>>>(p);
  kinit<<<dim3(618), dim3(256), 0, stream>>>(p);

  void* args[] = { &p };
  hipLaunchCooperativeKernel((const void*)kmain, dim3(300), dim3(256), args, 0, stream);

  kproj<<<dim3(4096), dim3(256), 0, stream>>>(p);
}

// Round 3
// 25159.212 us; speedup vs baseline: 1.6449x; 1.6449x over previous
//
#include <hip/hip_runtime.h>

typedef unsigned short u16;
typedef __attribute__((ext_vector_type(8))) short short8;   // 8 x bf16
typedef __attribute__((ext_vector_type(4))) float float4v;  // MFMA acc

// ---- output offsets (floats) ----
#define O_MEANS 0
#define O_LS    1310720
#define O_RHO   2621440
#define O_PI    3276800
#define O_EOS   3932160
#define O_H0H   3964928
#define O_H0C   3990528
#define O_H1H   4016128
#define O_H1C   4041728
#define O_H2H   4067328
#define O_H2C   4092928
#define O_PW    4118528
#define O_PK    4122368
#define O_AL    4123008

struct P {
  const float *strokes; const int *text; const int *tlen;
  const float *h0h,*h0c,*h1h,*h1c,*h2h,*h2c,*pw,*pk;
  const float *bih0,*bhh0,*bih1,*bhh1,*bih2,*bhh2;
  const float *Wwin,*bwin;
  const float *bmu,*bls,*brho,*bpi,*beos;
  u16 *B0,*B1,*B2,*Bw0,*BP;     // fragment-packed weights
  u16 *A0,*A1,*A2;              // fragment-packed activations per step
  u16 *y0,*y1,*y2;              // bf16 row-major hidden histories [T][64][400]
  float *obuf;                  // 3 x [30][64] rotating o-partials
  unsigned *bar;                // [0]=cnt [1]=gen
  float *out;
};

__device__ __forceinline__ u16 f2bf(float f){
  unsigned int x = __float_as_uint(f);
  unsigned int r = x + 0x7FFFu + ((x >> 16) & 1u);
  return (u16)(r >> 16);
}
// A-pack element (t, batch b, k) for a layer with KB k-blocks.
// block = (t*4 + b/16)*KB + k/32 ; inside: lane=((k>>3)&3)*16+(b&15), elem k&7
__device__ __forceinline__ size_t aidx(int t, int b, int k, int KB){
  return ((size_t)((t*4 + (b>>4))*KB + (k>>5)))*512
       + (size_t)(((((k>>3)&3)*16) + (b&15))*8 + (k&7));
}
__device__ __forceinline__ float sigm(float x){ return 1.f/(1.f+__expf(-x)); }
__device__ __forceinline__ float tanh_f(float x){ return 2.f/(1.f+__expf(-2.f*x)) - 1.f; }

// ---------------- weight packing ----------------
// layout [25 slices][4 tiles][KB][512]; tile col c(0..15): j = s*16+tile*4+(c&3),
// gate g = (c>>2)*400 + j  (i,f,g,o interleave)
__global__ void kpackB(const float* __restrict__ Wih, const float* __restrict__ Whh,
                       u16* __restrict__ dst, int KB, int kx, int stride, int total){
  int tid = blockIdx.x*256 + threadIdx.x;
  if (tid >= total) return;
  int e = tid & 511, blk = tid >> 9;
  int kb = blk % KB, tile = (blk / KB) & 3, s = blk / (KB*4);
  int lane = e >> 3, j = e & 7;
  int q = lane >> 4, n = lane & 15;
  int k = kb*32 + q*8 + j;
  int col = s*16 + tile*4 + (n&3);
  int g = (n>>2)*400 + col;
  float v = 0.f;
  if (k < kx) v = Wih[(size_t)g*stride + k];
  else if (k < kx + 400) v = Whh[(size_t)g*400 + (k - kx)];
  dst[tid] = f2bf(v);
}

// inline-w weights for L0: [25][4][2][512], from Wih0 cols 3..62
__global__ void kpackBw(const float* __restrict__ Wih0, u16* __restrict__ dst){
  int tid = blockIdx.x*256 + threadIdx.x;
  if (tid >= 25*4*2*512) return;
  int e = tid & 511, blk = tid >> 9;
  int kb = blk & 1, tile = (blk>>1) & 3, s = blk >> 3;
  int lane = e >> 3, j = e & 7;
  int q = lane >> 4, n = lane & 15;
  int k = kb*32 + q*8 + j;
  int col = s*16 + tile*4 + (n&3);
  int g = (n>>2)*400 + col;
  dst[tid] = (k < 60) ? f2bf(Wih0[(size_t)g*63 + 3 + k]) : (u16)0;
}

// projection weights: cols 0..39 mu, 40..79 ls, 80..99 rho, 100..119 pi, 120 eos
__global__ void kpackBP(const float* __restrict__ Wmu, const float* __restrict__ Wls,
                        const float* __restrict__ Wrho, const float* __restrict__ Wpi,
                        const float* __restrict__ Weos, u16* __restrict__ dst){
  int tid = blockIdx.x*256 + threadIdx.x;
  if (tid >= 8*38*512) return;
  int e = tid & 511, blk = tid >> 9;
  int lane = e >> 3, j = e & 7;
  int ns = blk / 38, kb = blk % 38;
  int q = lane >> 4, n = lane & 15;
  int k = kb*32 + q*8 + j;
  int col = ns*16 + n;
  float v = 0.f;
  if (k < 1200){
    if (col < 40)       v = Wmu[(size_t)col*1200 + k];
    else if (col < 80)  v = Wls[(size_t)(col-40)*1200 + k];
    else if (col < 100) v = Wrho[(size_t)(col-80)*1200 + k];
    else if (col < 120) v = Wpi[(size_t)(col-100)*1200 + k];
    else if (col == 120) v = Weos[k];
  }
  dst[tid] = f2bf(v);
}

// strokes rows + zero pads for all t (ws is 0xAA-poisoned every run)
__global__ void kfillA(P p){
  int tid = blockIdx.x*256 + threadIdx.x;
  if (tid >= 512*64*32) return;
  int it = tid & 31; int rr = tid >> 5; int b = rr & 63; int t = rr >> 6;
  const float* sx = p.strokes + ((size_t)t*64 + b)*3;
  if (it < 3)        p.A0[aidx(t,b,it,13)] = f2bf(sx[it]);
  else if (it < 16)  p.A0[aidx(t,b,400+it,13)] = 0;          // pads 403..415
  else if (it < 19)  p.A1[aidx(t,b,460+(it-16),27)] = f2bf(sx[it-16]);
  else if (it == 19) p.A1[aidx(t,b,863,27)] = 0;
  else if (it < 23)  p.A2[aidx(t,b,460+(it-20),27)] = f2bf(sx[it-20]);
  else if (it == 23) p.A2[aidx(t,b,863,27)] = 0;
}

// initial states + obuf/barrier zero
__global__ void kinit(P p){
  int tid = blockIdx.x*256 + threadIdx.x;
  if (tid < 25600){ int b=tid/400, j=tid%400; p.A0[aidx(0,b,3+j,13)] = f2bf(p.h0h[tid]); }
  else if (tid < 51200){ int i=tid-25600; int b=i/400, j=i%400; p.A1[aidx(0,b,463+j,27)] = f2bf(p.h1h[i]); }
  else if (tid < 76800){ int i=tid-51200; int b=i/400, j=i%400; p.A2[aidx(0,b,463+j,27)] = f2bf(p.h2h[i]); }
  else if (tid < 82560){ p.obuf[tid-76800] = 0.f; }
  else if (tid < 82568){ p.bar[tid-82560] = 0u; }
}

// ---------------- custom grid barrier (monotone generation) ----------------
// No cooperative API needed: 75 WGs on 256 CUs are always co-resident
// (__launch_bounds__(256,1); 2x 60.7KB LDS fits one CU). Bounded spin so a
// scheduling surprise yields a wrong answer, never a harness hang.
__device__ __forceinline__ void gsync(unsigned* bar, unsigned nwg, unsigned target){
  __syncthreads();
  if (threadIdx.x == 0){
    __threadfence();   // release: drain + wb dirty L2 so other XCDs see our writes
    unsigned prev = __hip_atomic_fetch_add(&bar[0], 1u, __ATOMIC_SEQ_CST, __HIP_MEMORY_SCOPE_AGENT);
    if (prev == nwg - 1u){
      __hip_atomic_store(&bar[0], 0u, __ATOMIC_RELAXED, __HIP_MEMORY_SCOPE_AGENT);
      __hip_atomic_store(&bar[1], target, __ATOMIC_RELEASE, __HIP_MEMORY_SCOPE_AGENT);
    } else {
      long cnt = 0;
      while (__hip_atomic_load(&bar[1], __ATOMIC_ACQUIRE, __HIP_MEMORY_SCOPE_AGENT) < target){
        __builtin_amdgcn_s_sleep(2);
        if (++cnt > (1L<<26)) break;   // failsafe
      }
    }
    __threadfence();   // acquire: invalidate L1/L2 before reading others' data
  }
  __syncthreads();
}

// ---------------- gate GEMM: one A-fragment shared by 4 column tiles ----------------
template<int KB>
__device__ __forceinline__ void gate_gemm(const u16* __restrict__ Ap, const u16* __restrict__ Bp,
                                          int t, int s, int lane, int wave, float4v* acc){
  const u16* Ab = Ap + ((size_t)(t*4 + wave)*KB)*512 + (size_t)lane*8;
  const u16* Bb = Bp + ((size_t)s*4*KB)*512 + (size_t)lane*8;
  #pragma unroll
  for (int kb = 0; kb < KB; ++kb){
    short8 af = *reinterpret_cast<const short8*>(Ab + (size_t)kb*512);
    #pragma unroll
    for (int tt = 0; tt < 4; ++tt){
      short8 bf = *reinterpret_cast<const short8*>(Bb + (size_t)(tt*KB + kb)*512);
      acc[tt] = __builtin_amdgcn_mfma_f32_16x16x32_bf16(af, bf, acc[tt], 0, 0, 0);
    }
  }
}

// ---------------- main persistent kernel: 75 WGs, 1 barrier/round ----------------
// grp0 (wg 0..24):  L0 at t=r   + window finalize w(r-1) + o-partials
// grp1 (wg 25..49): L1 at t=r-2
// grp2 (wg 50..74): L2 at t=r-3
__global__ __launch_bounds__(256, 1) void kmain(P p){
  const int wg = blockIdx.x, tid = threadIdx.x;
  const int lane = tid & 63, wave = tid >> 6;
  const int grp = (wg < 25) ? 0 : (wg < 50 ? 1 : 2);
  const int s = wg - grp*25;
  const int lag = (grp == 0) ? 0 : (grp + 1);   // 0,2,3

  __shared__ float ldsg[64][65];     // gate tile [b][4 tiles *16 cols]
  __shared__ float hsh[16][64];      // h0 stage for o-partials [jj][b]
  __shared__ float clds[16][64];     // persistent cell state   [jj][b]
  __shared__ float wacc[60][64];     // w accumulation f32      [l][b]
  __shared__ u16   wbf[64][80];      // w as MFMA A-operand     [b][k] (pad 80)
  __shared__ float klds[64][10];     // persistent kappa
  __shared__ float ash[64][10], bsh[64][10], ksh[64][10];

  const u16 *Ap, *Bp; u16 *yr;
  const float *bi, *bh, *cin; int ohh, occ;
  if (grp == 0){ Ap=p.A0; Bp=p.B0; yr=p.y0; bi=p.bih0; bh=p.bhh0; cin=p.h0c; ohh=O_H0H; occ=O_H0C; }
  else if (grp == 1){ Ap=p.A1; Bp=p.B1; yr=p.y1; bi=p.bih1; bh=p.bhh1; cin=p.h1c; ohh=O_H1H; occ=O_H1C; }
  else { Ap=p.A2; Bp=p.B2; yr=p.y2; bi=p.bih2; bh=p.bhh2; cin=p.h2c; ohh=O_H2H; occ=O_H2C; }

  for (int cell = tid; cell < 1024; cell += 256){
    int jj = cell >> 6, b = cell & 63;
    clds[jj][b] = cin[b*400 + s*16 + jj];
  }
  if (grp == 0){
    for (int cell = tid; cell < 640; cell += 256) klds[cell/10][cell%10] = p.pk[cell];
    for (int cell = tid; cell < 64*80; cell += 256){
      int b = cell/80, k = cell%80;
      wbf[b][k] = (k < 60) ? f2bf(p.pw[b*60 + k]) : (u16)0;
    }
  }
  __syncthreads();

  for (int r = 0; r < 515; ++r){
    // ---- window finalize for t = r-1 (replicated across the 25 L0 WGs) ----
    if (grp == 0 && r >= 1 && r <= 512){
      const int tw = r - 1;
      const float* ob = p.obuf + (size_t)((r-1)%3)*1920;
      for (int cell = tid; cell < 1920; cell += 256){
        int b = cell & 63, n = cell >> 6;
        float o = ob[n*64 + b] + p.bwin[n];
        if (n < 10) ash[b][n] = __expf(o);
        else if (n < 20) bsh[b][n-10] = __expf(o);
        else { float kn = klds[b][n-20] + 0.05f*__expf(o); klds[b][n-20] = kn; ksh[b][n-20] = kn; }
      }
      for (int cell = tid; cell < 3840; cell += 256) (&wacc[0][0])[cell] = 0.f;
      __syncthreads();
      for (int cell = tid; cell < 4096; cell += 256){
        int b = cell >> 6, u = cell & 63;
        float phi = 0.f;
        if (u < p.tlen[b]){
          #pragma unroll
          for (int n = 0; n < 10; ++n){
            float d = ksh[b][n] - (float)u;
            phi += ash[b][n]*__expf(-bsh[b][n]*d*d);
          }
          atomicAdd(&wacc[p.text[b*64 + u]][b], phi);
        }
        if (wg == 0) p.out[O_AL + ((size_t)tw*64 + b)*64 + u] = phi;
      }
      __syncthreads();
      for (int cell = tid; cell < 3840; cell += 256){
        int b = cell & 63, l = cell >> 6;
        u16 wv = f2bf(wacc[l][b]);
        wbf[b][l] = wv;
        if (wg == 1) p.A1[aidx(tw,b,400+l,27)] = wv;
        if (wg == 2) p.A2[aidx(tw,b,400+l,27)] = wv;
        if (wg == 0 && tw == 511) p.out[O_PW + b*60 + l] = wacc[l][b];
      }
      if (wg == 0 && tw == 511)
        for (int cell = tid; cell < 640; cell += 256) p.out[O_PK + cell] = klds[cell/10][cell%10];
      __syncthreads();
    }

    // ---- gate GEMM + LSTM pointwise ----
    const int t = r - lag;
    if (t >= 0 && t < 512){
      float4v acc[4] = {{0.f,0.f,0.f,0.f},{0.f,0.f,0.f,0.f},{0.f,0.f,0.f,0.f},{0.f,0.f,0.f,0.f}};
      if (grp == 0){
        gate_gemm<13>(Ap, Bp, t, s, lane, wave, acc);
        const int m = lane & 15, q = (lane >> 4) & 3;
        #pragma unroll
        for (int kb = 0; kb < 2; ++kb){
          short8 af = *reinterpret_cast<const short8*>(&wbf[wave*16 + m][kb*32 + q*8]);
          #pragma unroll
          for (int tt = 0; tt < 4; ++tt){
            short8 bf = *reinterpret_cast<const short8*>(
                p.Bw0 + ((size_t)((s*4 + tt)*2 + kb))*512 + (size_t)lane*8);
            acc[tt] = __builtin_amdgcn_mfma_f32_16x16x32_bf16(af, bf, acc[tt], 0, 0, 0);
          }
        }
      } else {
        gate_gemm<27>(Ap, Bp, t, s, lane, wave, acc);
      }
      {
        const int c = lane & 15, rb = wave*16 + ((lane>>4)<<2);
        #pragma unroll
        for (int tt = 0; tt < 4; ++tt)
          #pragma unroll
          for (int rr2 = 0; rr2 < 4; ++rr2)
            ldsg[rb+rr2][tt*16 + c] = acc[tt][rr2];
      }
      __syncthreads();
      for (int cell = tid; cell < 1024; cell += 256){
        int jj = cell >> 6, b = cell & 63;
        int j = s*16 + jj, tt = jj >> 2, jo = jj & 3;
        float gi = ldsg[b][tt*16 +      jo] + bi[j]      + bh[j];
        float gf = ldsg[b][tt*16 +  4 + jo] + bi[400+j]  + bh[400+j];
        float gg = ldsg[b][tt*16 +  8 + jo] + bi[800+j]  + bh[800+j];
        float go = ldsg[b][tt*16 + 12 + jo] + bi[1200+j] + bh[1200+j];
        float cp = clds[jj][b];
        float cn = sigm(gf)*cp + sigm(gi)*tanh_f(gg);
        float hh = sigm(go)*tanh_f(cn);
        clds[jj][b] = cn;
        u16 hb = f2bf(hh);
        yr[((size_t)t*64 + b)*400 + j] = hb;
        if (grp == 0){
          p.A1[aidx(t,b,j,27)] = hb;
          if (t < 511) p.A0[aidx(t+1,b,3+j,13)] = hb;
          hsh[jj][b] = hh;
        } else if (grp == 1){
          p.A2[aidx(t,b,j,27)] = hb;
          if (t < 511) p.A1[aidx(t+1,b,463+j,27)] = hb;
        } else {
          if (t < 511) p.A2[aidx(t+1,b,463+j,27)] = hb;
        }
        if (t == 511){ p.out[ohh + b*400 + j] = hh; p.out[occ + b*400 + j] = cn; }
      }
      if (grp == 0){
        __syncthreads();
        float* od = p.obuf + (size_t)(r%3)*1920;
        for (int cell = tid; cell < 1920; cell += 256){
          int b = cell & 63, n = cell >> 6;
          float sum = 0.f;
          #pragma unroll
          for (int jj = 0; jj < 16; ++jj)
            sum += hsh[jj][b] * p.Wwin[n*400 + s*16 + jj];
          atomicAdd(&od[n*64 + b], sum);
        }
      }
    }
    // rotate-zero the o-slot that round r+1 will write
    if (wg == 50 && r <= 510){
      float* oz = p.obuf + (size_t)((r+1)%3)*1920;
      for (int cell = tid; cell < 1920; cell += 256) oz[cell] = 0.f;
    }
    if (r < 514) gsync(p.bar, 75u, (unsigned)(r+1));
  }
}

// ---------------- output heads ----------------
__global__ __launch_bounds__(256) void kproj(P p){
  const int t = blockIdx.x >> 3, ns = blockIdx.x & 7;
  const int tid = threadIdx.x, lane = tid & 63, wave = tid >> 6;
  const int m = lane & 15, q = lane >> 4;
  float4v acc = {0.f,0.f,0.f,0.f};
  const size_t rowA = (size_t)t*64 + wave*16 + m;
  const u16* Bb = p.BP + ((size_t)ns*38)*512 + (size_t)lane*8;
  for (int kb = 0; kb < 38; ++kb){
    int k0 = kb*32 + q*8;
    const u16* src; int off;
    if (k0 < 400){ src = p.y0; off = k0; }
    else if (k0 < 800){ src = p.y1; off = k0 - 400; }
    else if (k0 < 1200){ src = p.y2; off = k0 - 800; }
    else { src = p.y0; off = 0; }     // B rows are zero for k>=1200
    short8 af = *reinterpret_cast<const short8*>(src + rowA*400 + off);
    short8 bf = *reinterpret_cast<const short8*>(Bb + (size_t)kb*512);
    acc = __builtin_amdgcn_mfma_f32_16x16x32_bf16(af, bf, acc, 0, 0, 0);
  }
  const int j = ns*16 + (lane & 15);
  const int bo = wave*16 + q*4;
  #pragma unroll
  for (int rr = 0; rr < 4; ++rr){
    float v = acc[rr];
    size_t ro = (size_t)t*64 + bo + rr;
    if (j < 40)        p.out[O_MEANS + ro*40 + j]        = v + p.bmu[j];
    else if (j < 80)   p.out[O_LS    + ro*40 + (j-40)]   = v + p.bls[j-40];
    else if (j < 100)  p.out[O_RHO   + ro*20 + (j-80)]   = tanhf(v + p.brho[j-80]);
    else if (j < 120)  p.out[O_PI    + ro*20 + (j-100)]  = v + p.bpi[j-100];
    else if (j == 120) p.out[O_EOS   + ro]               = v + p.beos[0];
  }
}

// ---------------- host ----------------
extern "C" void kernel_launch(void* const* d_in, const int* in_sizes, int n_in,
                              void* d_out, int out_size, void* d_ws, size_t ws_size,
                              hipStream_t stream){
  P p;
  p.strokes = (const float*)d_in[0];
  p.text    = (const int*)  d_in[1];
  p.tlen    = (const int*)  d_in[2];
  p.h0h = (const float*)d_in[3];  p.h0c = (const float*)d_in[4];
  p.h1h = (const float*)d_in[5];  p.h1c = (const float*)d_in[6];
  p.h2h = (const float*)d_in[7];  p.h2c = (const float*)d_in[8];
  p.pw  = (const float*)d_in[9];  p.pk  = (const float*)d_in[10];
  const float* Wih0 = (const float*)d_in[11]; const float* Whh0 = (const float*)d_in[12];
  p.bih0 = (const float*)d_in[13]; p.bhh0 = (const float*)d_in[14];
  const float* Wih1 = (const float*)d_in[15]; const float* Whh1 = (const float*)d_in[16];
  p.bih1 = (const float*)d_in[17]; p.bhh1 = (const float*)d_in[18];
  const float* Wih2 = (const float*)d_in[19]; const float* Whh2 = (const float*)d_in[20];
  p.bih2 = (const float*)d_in[21]; p.bhh2 = (const float*)d_in[22];
  p.Wwin = (const float*)d_in[23]; p.bwin = (const float*)d_in[24];
  const float* Wmu  = (const float*)d_in[25]; p.bmu  = (const float*)d_in[26];
  const float* Wls  = (const float*)d_in[27]; p.bls  = (const float*)d_in[28];
  const float* Wrho = (const float*)d_in[29]; p.brho = (const float*)d_in[30];
  const float* Wpi  = (const float*)d_in[31]; p.bpi  = (const float*)d_in[32];
  const float* Weos = (const float*)d_in[33]; p.beos = (const float*)d_in[34];
  p.out = (float*)d_out;

  char* w = (char*)d_ws; size_t off = 0;
  auto alloc = [&](size_t bytes)->void*{ void* r = w + off; off += (bytes + 511) & ~(size_t)511; return r; };
  p.B0  = (u16*)alloc((size_t)25*4*13*512*2);
  p.B1  = (u16*)alloc((size_t)25*4*27*512*2);
  p.B2  = (u16*)alloc((size_t)25*4*27*512*2);
  p.Bw0 = (u16*)alloc((size_t)25*4*2*512*2);
  p.BP  = (u16*)alloc((size_t)8*38*512*2);
  p.A0  = (u16*)alloc((size_t)512*4*13*512*2);
  p.A1  = (u16*)alloc((size_t)512*4*27*512*2);
  p.A2  = (u16*)alloc((size_t)512*4*27*512*2);
  p.y0  = (u16*)alloc((size_t)512*64*400*2);
  p.y1  = (u16*)alloc((size_t)512*64*400*2);
  p.y2  = (u16*)alloc((size_t)512*64*400*2);
  p.obuf= (float*)alloc((size_t)3*1920*4);
  p.bar = (unsigned*)alloc(256);

  kpackB<<<dim3(2600), dim3(256), 0, stream>>>(Wih0, Whh0, p.B0, 13, 3,   63,  25*4*13*512);
  kpackB<<<dim3(5400), dim3(256), 0, stream>>>(Wih1, Whh1, p.B1, 27, 463, 463, 25*4*27*512);
  kpackB<<<dim3(5400), dim3(256), 0, stream>>>(Wih2, Whh2, p.B2, 27, 463, 463, 25*4*27*512);
  kpackBw<<<dim3(400), dim3(256), 0, stream>>>(Wih0, p.Bw0);
  kpackBP<<<dim3(608), dim3(256), 0, stream>>>(Wmu, Wls, Wrho, Wpi, Weos, p.BP);
  kfillA<<<dim3(4096), dim3(256), 0, stream>>>(p);
  kinit<<<dim3(323), dim3(256), 0, stream>>>(p);

  // plain launch: custom barrier needs no cooperative API; 75 WGs are
  // co-resident by construction (1 WG/CU min occupancy, 256 CUs).
  kmain<<<dim3(75), dim3(256), 0, stream>>>(p);

  kproj<<<dim3(4096), dim3(256), 0, stream>>>(p);
}

// Round 4
// 12949.701 us; speedup vs baseline: 3.1959x; 1.9428x over previous
//
#include <hip/hip_runtime.h>

typedef unsigned short u16;
typedef __attribute__((ext_vector_type(8))) short short8;   // 8 x bf16
typedef __attribute__((ext_vector_type(4))) float float4v;  // MFMA acc

// ---- output offsets (floats) ----
#define O_MEANS 0
#define O_LS    1310720
#define O_RHO   2621440
#define O_PI    3276800
#define O_EOS   3932160
#define O_H0H   3964928
#define O_H0C   3990528
#define O_H1H   4016128
#define O_H1C   4041728
#define O_H2H   4067328
#define O_H2C   4092928
#define O_PW    4118528
#define O_PK    4122368
#define O_AL    4123008

struct P {
  const float *strokes; const int *text; const int *tlen;
  const float *h0h,*h0c,*h1h,*h1c,*h2h,*h2c,*pw,*pk;
  const float *bih0,*bhh0,*bih1,*bhh1,*bih2,*bhh2;
  const float *Wwin,*bwin;
  const float *bmu,*bls,*brho,*bpi,*beos;
  u16 *B0,*B1,*B2,*Bw0,*BP;     // fragment-packed weights
  u16 *A0,*A1,*A2;              // fragment-packed activations per step
  u16 *y0,*y1,*y2;              // bf16 row-major hidden histories [T][64][400]
  float *obuf;                  // 3 x [30][64] rotating o-partials
  unsigned *bar;                // [0]=cnt [1]=gen
  float *out;
};

__device__ __forceinline__ u16 f2bf(float f){
  unsigned int x = __float_as_uint(f);
  unsigned int r = x + 0x7FFFu + ((x >> 16) & 1u);
  return (u16)(r >> 16);
}
// A-pack element (t, batch b, k) for a layer with KB k-blocks.
// block = (t*4 + b/16)*KB + k/32 ; inside: lane=((k>>3)&3)*16+(b&15), elem k&7
__device__ __forceinline__ size_t aidx(int t, int b, int k, int KB){
  return ((size_t)((t*4 + (b>>4))*KB + (k>>5)))*512
       + (size_t)(((((k>>3)&3)*16) + (b&15))*8 + (k&7));
}
__device__ __forceinline__ float sigm(float x){ return 1.f/(1.f+__expf(-x)); }
__device__ __forceinline__ float tanh_f(float x){ return 2.f/(1.f+__expf(-2.f*x)) - 1.f; }

// ---------------- weight packing ----------------
// layout [25 slices][4 tiles][KB][512]; tile col c(0..15): j = s*16+tile*4+(c&3),
// gate g = (c>>2)*400 + j  (i,f,g,o interleave)
__global__ void kpackB(const float* __restrict__ Wih, const float* __restrict__ Whh,
                       u16* __restrict__ dst, int KB, int kx, int stride, int total){
  int tid = blockIdx.x*256 + threadIdx.x;
  if (tid >= total) return;
  int e = tid & 511, blk = tid >> 9;
  int kb = blk % KB, tile = (blk / KB) & 3, s = blk / (KB*4);
  int lane = e >> 3, j = e & 7;
  int q = lane >> 4, n = lane & 15;
  int k = kb*32 + q*8 + j;
  int col = s*16 + tile*4 + (n&3);
  int g = (n>>2)*400 + col;
  float v = 0.f;
  if (k < kx) v = Wih[(size_t)g*stride + k];
  else if (k < kx + 400) v = Whh[(size_t)g*400 + (k - kx)];
  dst[tid] = f2bf(v);
}

// inline-w weights for L0: [25][4][2][512], from Wih0 cols 3..62
__global__ void kpackBw(const float* __restrict__ Wih0, u16* __restrict__ dst){
  int tid = blockIdx.x*256 + threadIdx.x;
  if (tid >= 25*4*2*512) return;
  int e = tid & 511, blk = tid >> 9;
  int kb = blk & 1, tile = (blk>>1) & 3, s = blk >> 3;
  int lane = e >> 3, j = e & 7;
  int q = lane >> 4, n = lane & 15;
  int k = kb*32 + q*8 + j;
  int col = s*16 + tile*4 + (n&3);
  int g = (n>>2)*400 + col;
  dst[tid] = (k < 60) ? f2bf(Wih0[(size_t)g*63 + 3 + k]) : (u16)0;
}

// projection weights: cols 0..39 mu, 40..79 ls, 80..99 rho, 100..119 pi, 120 eos
__global__ void kpackBP(const float* __restrict__ Wmu, const float* __restrict__ Wls,
                        const float* __restrict__ Wrho, const float* __restrict__ Wpi,
                        const float* __restrict__ Weos, u16* __restrict__ dst){
  int tid = blockIdx.x*256 + threadIdx.x;
  if (tid >= 8*38*512) return;
  int e = tid & 511, blk = tid >> 9;
  int lane = e >> 3, j = e & 7;
  int ns = blk / 38, kb = blk % 38;
  int q = lane >> 4, n = lane & 15;
  int k = kb*32 + q*8 + j;
  int col = ns*16 + n;
  float v = 0.f;
  if (k < 1200){
    if (col < 40)       v = Wmu[(size_t)col*1200 + k];
    else if (col < 80)  v = Wls[(size_t)(col-40)*1200 + k];
    else if (col < 100) v = Wrho[(size_t)(col-80)*1200 + k];
    else if (col < 120) v = Wpi[(size_t)(col-100)*1200 + k];
    else if (col == 120) v = Weos[k];
  }
  dst[tid] = f2bf(v);
}

// strokes rows + zero pads for all t (ws is 0xAA-poisoned every run)
__global__ void kfillA(P p){
  int tid = blockIdx.x*256 + threadIdx.x;
  if (tid >= 512*64*32) return;
  int it = tid & 31; int rr = tid >> 5; int b = rr & 63; int t = rr >> 6;
  const float* sx = p.strokes + ((size_t)t*64 + b)*3;
  if (it < 3)        p.A0[aidx(t,b,it,13)] = f2bf(sx[it]);
  else if (it < 16)  p.A0[aidx(t,b,400+it,13)] = 0;          // pads 403..415
  else if (it < 19)  p.A1[aidx(t,b,460+(it-16),27)] = f2bf(sx[it-16]);
  else if (it == 19) p.A1[aidx(t,b,863,27)] = 0;
  else if (it < 23)  p.A2[aidx(t,b,460+(it-20),27)] = f2bf(sx[it-20]);
  else if (it == 23) p.A2[aidx(t,b,863,27)] = 0;
}

// initial states + obuf/barrier zero
__global__ void kinit(P p){
  int tid = blockIdx.x*256 + threadIdx.x;
  if (tid < 25600){ int b=tid/400, j=tid%400; p.A0[aidx(0,b,3+j,13)] = f2bf(p.h0h[tid]); }
  else if (tid < 51200){ int i=tid-25600; int b=i/400, j=i%400; p.A1[aidx(0,b,463+j,27)] = f2bf(p.h1h[i]); }
  else if (tid < 76800){ int i=tid-51200; int b=i/400, j=i%400; p.A2[aidx(0,b,463+j,27)] = f2bf(p.h2h[i]); }
  else if (tid < 82560){ p.obuf[tid-76800] = 0.f; }
  else if (tid < 82568){ p.bar[tid-82560] = 0u; }
}

// ---------------- custom grid barrier ----------------
// RELEASE on the arrival RMW does the pre-barrier L2 writeback; one acquire
// fence after the spin does the post-barrier invalidate. Weights live in LDS,
// so the invalidate no longer costs a weight refetch.
__device__ __forceinline__ void gsync(unsigned* bar, unsigned nwg, unsigned target){
  __syncthreads();
  if (threadIdx.x == 0){
    unsigned prev = __hip_atomic_fetch_add(&bar[0], 1u, __ATOMIC_RELEASE, __HIP_MEMORY_SCOPE_AGENT);
    if (prev == nwg - 1u){
      __hip_atomic_store(&bar[0], 0u, __ATOMIC_RELAXED, __HIP_MEMORY_SCOPE_AGENT);
      __hip_atomic_store(&bar[1], target, __ATOMIC_RELEASE, __HIP_MEMORY_SCOPE_AGENT);
    } else {
      long cnt = 0;
      while (__hip_atomic_load(&bar[1], __ATOMIC_RELAXED, __HIP_MEMORY_SCOPE_AGENT) < target){
        __builtin_amdgcn_s_sleep(2);
        if (++cnt > (1L<<26)) break;   // failsafe: wrong answer, never a hang
      }
    }
    __builtin_amdgcn_fence(__ATOMIC_ACQUIRE, "agent");  // inv L1/L2 before cross-WG reads
  }
  __syncthreads();
}

// ---------------- gate GEMM: A from global (IC), B from LDS ----------------
template<int KB>
__device__ __forceinline__ void gate_gemm(const u16* __restrict__ Ap, const u16* wBl,
                                          int t, int lane, int wave, float4v* acc){
  const u16* Ab = Ap + ((size_t)(t*4 + wave)*KB)*512 + (size_t)lane*8;
  const u16* Bb = wBl + lane*8;
  #pragma unroll
  for (int kb = 0; kb < KB; ++kb){
    short8 af = *reinterpret_cast<const short8*>(Ab + (size_t)kb*512);
    #pragma unroll
    for (int tt = 0; tt < 4; ++tt){
      short8 bf = *reinterpret_cast<const short8*>(Bb + (size_t)(tt*KB + kb)*512);
      acc[tt] = __builtin_amdgcn_mfma_f32_16x16x32_bf16(af, bf, acc[tt], 0, 0, 0);
    }
  }
}

// ---------------- main persistent kernel: 75 WGs, 1 barrier/round ----------------
// grp0 (wg 0..24):  L0 at t=r   + window finalize w(r-1) + o-partials
// grp1 (wg 25..49): L1 at t=r-2
// grp2 (wg 50..74): L2 at t=r-3
// Weights persist in LDS: grp1/2 slice = 110.6KB; grp0 = 61.4KB weights +
// 39.9KB window scratch overlaid in the same 110.6KB region.
// Static LDS total: 110592 + 16640 + 4096 = 131328 B (<160 KiB, 1 WG/CU).
__global__ __launch_bounds__(256, 1) void kmain(P p){
  const int wg = blockIdx.x, tid = threadIdx.x;
  const int lane = tid & 63, wave = tid >> 6;
  const int grp = (wg < 25) ? 0 : (wg < 50 ? 1 : 2);
  const int s = wg - grp*25;
  const int lag = (grp == 0) ? 0 : (grp + 1);   // 0,2,3

  __shared__ u16  wB[55296];         // 110592 B weight slice (+ grp0 overlay)
  __shared__ float ldsg[64][65];     // gate tile [b][4 tiles *16 cols]
  __shared__ float clds[16][64];     // persistent cell state [jj][b]

  // grp0 overlays in wB[30720..55295] (49152 B available, 39936 used)
  u16* wBw = wB + 26624;                                   // 8 KB inline-w weights
  char* exb = (char*)(wB + 30720);
  float (*hsh)[64]  = (float (*)[64])(exb);                //  4096 B  h0 stage
  float (*wacc)[64] = (float (*)[64])(exb + 4096);         // 15360 B  w accum
  u16   (*wbf)[80]  = (u16   (*)[80])(exb + 19456);        // 10240 B  w A-operand
  float (*klds)[10] = (float (*)[10])(exb + 29696);        //  2560 B  kappa
  float (*ash)[10]  = (float (*)[10])(exb + 32256);
  float (*bsh)[10]  = (float (*)[10])(exb + 34816);
  float (*ksh)[10]  = (float (*)[10])(exb + 37376);        // end 39936

  const u16 *Ap; u16 *yr;
  const float *bi, *bh, *cin; int ohh, occ;
  if (grp == 0){ Ap=p.A0; yr=p.y0; bi=p.bih0; bh=p.bhh0; cin=p.h0c; ohh=O_H0H; occ=O_H0C; }
  else if (grp == 1){ Ap=p.A1; yr=p.y1; bi=p.bih1; bh=p.bhh1; cin=p.h1c; ohh=O_H1H; occ=O_H1C; }
  else { Ap=p.A2; yr=p.y2; bi=p.bih2; bh=p.bhh2; cin=p.h2c; ohh=O_H2H; occ=O_H2C; }

  // ---- stage weight slice into LDS (once) ----
  {
    const u16* gsrc; int cnt;
    if (grp == 0){ gsrc = p.B0 + (size_t)s*26624; cnt = 26624; }
    else if (grp == 1){ gsrc = p.B1 + (size_t)s*55296; cnt = 55296; }
    else { gsrc = p.B2 + (size_t)s*55296; cnt = 55296; }
    for (int i = tid*8; i < cnt; i += 2048)
      *reinterpret_cast<short8*>(&wB[i]) = *reinterpret_cast<const short8*>(gsrc + i);
    if (grp == 0){
      const u16* gw = p.Bw0 + (size_t)s*4096;
      for (int i = tid*8; i < 4096; i += 2048)
        *reinterpret_cast<short8*>(wBw + i) = *reinterpret_cast<const short8*>(gw + i);
    }
  }

  for (int cell = tid; cell < 1024; cell += 256){
    int jj = cell >> 6, b = cell & 63;
    clds[jj][b] = cin[b*400 + s*16 + jj];
  }
  if (grp == 0){
    for (int cell = tid; cell < 640; cell += 256) klds[cell/10][cell%10] = p.pk[cell];
    for (int cell = tid; cell < 64*80; cell += 256){
      int b = cell/80, k = cell%80;
      wbf[b][k] = (k < 60) ? f2bf(p.pw[b*60 + k]) : (u16)0;
    }
  }
  __syncthreads();

  for (int r = 0; r < 515; ++r){
    // ---- window finalize for t = r-1 (replicated across the 25 L0 WGs) ----
    if (grp == 0 && r >= 1 && r <= 512){
      const int tw = r - 1;
      const float* ob = p.obuf + (size_t)((r-1)%3)*1920;
      for (int cell = tid; cell < 1920; cell += 256){
        int b = cell & 63, n = cell >> 6;
        float o = ob[n*64 + b] + p.bwin[n];
        if (n < 10) ash[b][n] = __expf(o);
        else if (n < 20) bsh[b][n-10] = __expf(o);
        else { float kn = klds[b][n-20] + 0.05f*__expf(o); klds[b][n-20] = kn; ksh[b][n-20] = kn; }
      }
      for (int cell = tid; cell < 3840; cell += 256) ((float*)wacc)[cell] = 0.f;
      __syncthreads();
      for (int cell = tid; cell < 4096; cell += 256){
        int b = cell >> 6, u = cell & 63;
        float phi = 0.f;
        if (u < p.tlen[b]){
          #pragma unroll
          for (int n = 0; n < 10; ++n){
            float d = ksh[b][n] - (float)u;
            phi += ash[b][n]*__expf(-bsh[b][n]*d*d);
          }
          atomicAdd(&wacc[p.text[b*64 + u]][b], phi);
        }
        if (wg == 0) p.out[O_AL + ((size_t)tw*64 + b)*64 + u] = phi;
      }
      __syncthreads();
      for (int cell = tid; cell < 3840; cell += 256){
        int b = cell & 63, l = cell >> 6;
        u16 wv = f2bf(wacc[l][b]);
        wbf[b][l] = wv;
        if (wg == 1) p.A1[aidx(tw,b,400+l,27)] = wv;
        if (wg == 2) p.A2[aidx(tw,b,400+l,27)] = wv;
        if (wg == 0 && tw == 511) p.out[O_PW + b*60 + l] = wacc[l][b];
      }
      if (wg == 0 && tw == 511)
        for (int cell = tid; cell < 640; cell += 256) p.out[O_PK + cell] = klds[cell/10][cell%10];
      __syncthreads();
    }

    // ---- gate GEMM + LSTM pointwise ----
    const int t = r - lag;
    if (t >= 0 && t < 512){
      float4v acc[4] = {{0.f,0.f,0.f,0.f},{0.f,0.f,0.f,0.f},{0.f,0.f,0.f,0.f},{0.f,0.f,0.f,0.f}};
      if (grp == 0){
        gate_gemm<13>(Ap, wB, t, lane, wave, acc);
        const int m = lane & 15, q = (lane >> 4) & 3;
        #pragma unroll
        for (int kb = 0; kb < 2; ++kb){
          short8 af = *reinterpret_cast<const short8*>(&wbf[wave*16 + m][kb*32 + q*8]);
          #pragma unroll
          for (int tt = 0; tt < 4; ++tt){
            short8 bf = *reinterpret_cast<const short8*>(wBw + (size_t)((tt*2 + kb))*512 + (size_t)lane*8);
            acc[tt] = __builtin_amdgcn_mfma_f32_16x16x32_bf16(af, bf, acc[tt], 0, 0, 0);
          }
        }
      } else {
        gate_gemm<27>(Ap, wB, t, lane, wave, acc);
      }
      {
        const int c = lane & 15, rb = wave*16 + ((lane>>4)<<2);
        #pragma unroll
        for (int tt = 0; tt < 4; ++tt)
          #pragma unroll
          for (int rr2 = 0; rr2 < 4; ++rr2)
            ldsg[rb+rr2][tt*16 + c] = acc[tt][rr2];
      }
      __syncthreads();
      for (int cell = tid; cell < 1024; cell += 256){
        int jj = cell >> 6, b = cell & 63;
        int j = s*16 + jj, tt = jj >> 2, jo = jj & 3;
        float gi = ldsg[b][tt*16 +      jo] + bi[j]      + bh[j];
        float gf = ldsg[b][tt*16 +  4 + jo] + bi[400+j]  + bh[400+j];
        float gg = ldsg[b][tt*16 +  8 + jo] + bi[800+j]  + bh[800+j];
        float go = ldsg[b][tt*16 + 12 + jo] + bi[1200+j] + bh[1200+j];
        float cp = clds[jj][b];
        float cn = sigm(gf)*cp + sigm(gi)*tanh_f(gg);
        float hh = sigm(go)*tanh_f(cn);
        clds[jj][b] = cn;
        u16 hb = f2bf(hh);
        yr[((size_t)t*64 + b)*400 + j] = hb;
        if (grp == 0){
          p.A1[aidx(t,b,j,27)] = hb;
          if (t < 511) p.A0[aidx(t+1,b,3+j,13)] = hb;
          hsh[jj][b] = hh;
        } else if (grp == 1){
          p.A2[aidx(t,b,j,27)] = hb;
          if (t < 511) p.A1[aidx(t+1,b,463+j,27)] = hb;
        } else {
          if (t < 511) p.A2[aidx(t+1,b,463+j,27)] = hb;
        }
        if (t == 511){ p.out[ohh + b*400 + j] = hh; p.out[occ + b*400 + j] = cn; }
      }
      if (grp == 0){
        __syncthreads();
        float* od = p.obuf + (size_t)(r%3)*1920;
        for (int cell = tid; cell < 1920; cell += 256){
          int b = cell & 63, n = cell >> 6;
          float sum = 0.f;
          #pragma unroll
          for (int jj = 0; jj < 16; ++jj)
            sum += hsh[jj][b] * p.Wwin[n*400 + s*16 + jj];
          atomicAdd(&od[n*64 + b], sum);
        }
      }
    }
    // rotate-zero the o-slot that round r+1 will write
    if (wg == 50 && r <= 510){
      float* oz = p.obuf + (size_t)((r+1)%3)*1920;
      for (int cell = tid; cell < 1920; cell += 256) oz[cell] = 0.f;
    }
    if (r < 514) gsync(p.bar, 75u, (unsigned)(r+1));
  }
}

// ---------------- output heads ----------------
__global__ __launch_bounds__(256) void kproj(P p){
  const int t = blockIdx.x >> 3, ns = blockIdx.x & 7;
  const int tid = threadIdx.x, lane = tid & 63, wave = tid >> 6;
  const int m = lane & 15, q = lane >> 4;
  float4v acc = {0.f,0.f,0.f,0.f};
  const size_t rowA = (size_t)t*64 + wave*16 + m;
  const u16* Bb = p.BP + ((size_t)ns*38)*512 + (size_t)lane*8;
  for (int kb = 0; kb < 38; ++kb){
    int k0 = kb*32 + q*8;
    const u16* src; int off;
    if (k0 < 400){ src = p.y0; off = k0; }
    else if (k0 < 800){ src = p.y1; off = k0 - 400; }
    else if (k0 < 1200){ src = p.y2; off = k0 - 800; }
    else { src = p.y0; off = 0; }     // B rows are zero for k>=1200
    short8 af = *reinterpret_cast<const short8*>(src + rowA*400 + off);
    short8 bf = *reinterpret_cast<const short8*>(Bb + (size_t)kb*512);
    acc = __builtin_amdgcn_mfma_f32_16x16x32_bf16(af, bf, acc, 0, 0, 0);
  }
  const int j = ns*16 + (lane & 15);
  const int bo = wave*16 + q*4;
  #pragma unroll
  for (int rr = 0; rr < 4; ++rr){
    float v = acc[rr];
    size_t ro = (size_t)t*64 + bo + rr;
    if (j < 40)        p.out[O_MEANS + ro*40 + j]        = v + p.bmu[j];
    else if (j < 80)   p.out[O_LS    + ro*40 + (j-40)]   = v + p.bls[j-40];
    else if (j < 100)  p.out[O_RHO   + ro*20 + (j-80)]   = tanhf(v + p.brho[j-80]);
    else if (j < 120)  p.out[O_PI    + ro*20 + (j-100)]  = v + p.bpi[j-100];
    else if (j == 120) p.out[O_EOS   + ro]               = v + p.beos[0];
  }
}

// ---------------- host ----------------
extern "C" void kernel_launch(void* const* d_in, const int* in_sizes, int n_in,
                              void* d_out, int out_size, void* d_ws, size_t ws_size,
                              hipStream_t stream){
  P p;
  p.strokes = (const float*)d_in[0];
  p.text    = (const int*)  d_in[1];
  p.tlen    = (const int*)  d_in[2];
  p.h0h = (const float*)d_in[3];  p.h0c = (const float*)d_in[4];
  p.h1h = (const float*)d_in[5];  p.h1c = (const float*)d_in[6];
  p.h2h = (const float*)d_in[7];  p.h2c = (const float*)d_in[8];
  p.pw  = (const float*)d_in[9];  p.pk  = (const float*)d_in[10];
  const float* Wih0 = (const float*)d_in[11]; const float* Whh0 = (const float*)d_in[12];
  p.bih0 = (const float*)d_in[13]; p.bhh0 = (const float*)d_in[14];
  const float* Wih1 = (const float*)d_in[15]; const float* Whh1 = (const float*)d_in[16];
  p.bih1 = (const float*)d_in[17]; p.bhh1 = (const float*)d_in[18];
  const float* Wih2 = (const float*)d_in[19]; const float* Whh2 = (const float*)d_in[20];
  p.bih2 = (const float*)d_in[21]; p.bhh2 = (const float*)d_in[22];
  p.Wwin = (const float*)d_in[23]; p.bwin = (const float*)d_in[24];
  const float* Wmu  = (const float*)d_in[25]; p.bmu  = (const float*)d_in[26];
  const float* Wls  = (const float*)d_in[27]; p.bls  = (const float*)d_in[28];
  const float* Wrho = (const float*)d_in[29]; p.brho = (const float*)d_in[30];
  const float* Wpi  = (const float*)d_in[31]; p.bpi  = (const float*)d_in[32];
  const float* Weos = (const float*)d_in[33]; p.beos = (const float*)d_in[34];
  p.out = (float*)d_out;

  char* w = (char*)d_ws; size_t off = 0;
  auto alloc = [&](size_t bytes)->void*{ void* r = w + off; off += (bytes + 511) & ~(size_t)511; return r; };
  p.B0  = (u16*)alloc((size_t)25*4*13*512*2);
  p.B1  = (u16*)alloc((size_t)25*4*27*512*2);
  p.B2  = (u16*)alloc((size_t)25*4*27*512*2);
  p.Bw0 = (u16*)alloc((size_t)25*4*2*512*2);
  p.BP  = (u16*)alloc((size_t)8*38*512*2);
  p.A0  = (u16*)alloc((size_t)512*4*13*512*2);
  p.A1  = (u16*)alloc((size_t)512*4*27*512*2);
  p.A2  = (u16*)alloc((size_t)512*4*27*512*2);
  p.y0  = (u16*)alloc((size_t)512*64*400*2);
  p.y1  = (u16*)alloc((size_t)512*64*400*2);
  p.y2  = (u16*)alloc((size_t)512*64*400*2);
  p.obuf= (float*)alloc((size_t)3*1920*4);
  p.bar = (unsigned*)alloc(256);

  kpackB<<<dim3(2600), dim3(256), 0, stream>>>(Wih0, Whh0, p.B0, 13, 3,   63,  25*4*13*512);
  kpackB<<<dim3(5400), dim3(256), 0, stream>>>(Wih1, Whh1, p.B1, 27, 463, 463, 25*4*27*512);
  kpackB<<<dim3(5400), dim3(256), 0, stream>>>(Wih2, Whh2, p.B2, 27, 463, 463, 25*4*27*512);
  kpackBw<<<dim3(400), dim3(256), 0, stream>>>(Wih0, p.Bw0);
  kpackBP<<<dim3(608), dim3(256), 0, stream>>>(Wmu, Wls, Wrho, Wpi, Weos, p.BP);
  kfillA<<<dim3(4096), dim3(256), 0, stream>>>(p);
  kinit<<<dim3(323), dim3(256), 0, stream>>>(p);

  // plain launch: custom barrier needs no cooperative API; 75 WGs are
  // co-resident by construction (1 WG/CU min occupancy, 256 CUs).
  kmain<<<dim3(75), dim3(256), 0, stream>>>(p);

  kproj<<<dim3(4096), dim3(256), 0, stream>>>(p);
}

// Round 5
// 10250.764 us; speedup vs baseline: 4.0373x; 1.2633x over previous
//
#include <hip/hip_runtime.h>

typedef unsigned short u16;
typedef __attribute__((ext_vector_type(8))) short short8;   // 8 x bf16
typedef __attribute__((ext_vector_type(4))) float float4v;  // MFMA acc

// ---- output offsets (floats) ----
#define O_MEANS 0
#define O_LS    1310720
#define O_RHO   2621440
#define O_PI    3276800
#define O_EOS   3932160
#define O_H0H   3964928
#define O_H0C   3990528
#define O_H1H   4016128
#define O_H1C   4041728
#define O_H2H   4067328
#define O_H2C   4092928
#define O_PW    4118528
#define O_PK    4122368
#define O_AL    4123008

#define GEN_IDX 2400   // bar: [wg*32] arrival flags (128B apart), [2400] generation

struct P {
  const float *strokes; const int *text; const int *tlen;
  const float *h0h,*h0c,*h1h,*h1c,*h2h,*h2c,*pw,*pk;
  const float *bih0,*bhh0,*bih1,*bhh1,*bih2,*bhh2;
  const float *Wwin,*bwin;
  const float *bmu,*bls,*brho,*bpi,*beos;
  u16 *B0,*B1,*B2,*Bw0,*BP;     // fragment-packed weights
  u16 *A0,*A1,*A2;              // fragment-packed activations per step
  u16 *y0,*y1,*y2;              // bf16 row-major hidden histories [T][64][400]
  float *obuf;                  // 3 x [30][64] rotating o-partials
  unsigned *bar;                // padded arrival flags + gen
  float *out;
};

__device__ __forceinline__ u16 f2bf(float f){
  unsigned int x = __float_as_uint(f);
  unsigned int r = x + 0x7FFFu + ((x >> 16) & 1u);
  return (u16)(r >> 16);
}
// A-pack element (t, batch b, k) for a layer with KB k-blocks.
// block = (t*4 + b/16)*KB + k/32 ; inside: lane=((k>>3)&3)*16+(b&15), elem k&7
__device__ __forceinline__ size_t aidx(int t, int b, int k, int KB){
  return ((size_t)((t*4 + (b>>4))*KB + (k>>5)))*512
       + (size_t)(((((k>>3)&3)*16) + (b&15))*8 + (k&7));
}
__device__ __forceinline__ float sigm(float x){ return 1.f/(1.f+__expf(-x)); }
__device__ __forceinline__ float tanh_f(float x){ return 2.f/(1.f+__expf(-2.f*x)) - 1.f; }

// ---------------- weight packing ----------------
// layout [25 slices][4 tiles][KB][512]; tile col c(0..15): j = s*16+tile*4+(c&3),
// gate g = (c>>2)*400 + j  (i,f,g,o interleave)
__global__ void kpackB(const float* __restrict__ Wih, const float* __restrict__ Whh,
                       u16* __restrict__ dst, int KB, int kx, int stride, int total){
  int tid = blockIdx.x*256 + threadIdx.x;
  if (tid >= total) return;
  int e = tid & 511, blk = tid >> 9;
  int kb = blk % KB, tile = (blk / KB) & 3, s = blk / (KB*4);
  int lane = e >> 3, j = e & 7;
  int q = lane >> 4, n = lane & 15;
  int k = kb*32 + q*8 + j;
  int col = s*16 + tile*4 + (n&3);
  int g = (n>>2)*400 + col;
  float v = 0.f;
  if (k < kx) v = Wih[(size_t)g*stride + k];
  else if (k < kx + 400) v = Whh[(size_t)g*400 + (k - kx)];
  dst[tid] = f2bf(v);
}

// inline-w weights for L0: [25][4][2][512], from Wih0 cols 3..62
__global__ void kpackBw(const float* __restrict__ Wih0, u16* __restrict__ dst){
  int tid = blockIdx.x*256 + threadIdx.x;
  if (tid >= 25*4*2*512) return;
  int e = tid & 511, blk = tid >> 9;
  int kb = blk & 1, tile = (blk>>1) & 3, s = blk >> 3;
  int lane = e >> 3, j = e & 7;
  int q = lane >> 4, n = lane & 15;
  int k = kb*32 + q*8 + j;
  int col = s*16 + tile*4 + (n&3);
  int g = (n>>2)*400 + col;
  dst[tid] = (k < 60) ? f2bf(Wih0[(size_t)g*63 + 3 + k]) : (u16)0;
}

// projection weights: cols 0..39 mu, 40..79 ls, 80..99 rho, 100..119 pi, 120 eos
__global__ void kpackBP(const float* __restrict__ Wmu, const float* __restrict__ Wls,
                        const float* __restrict__ Wrho, const float* __restrict__ Wpi,
                        const float* __restrict__ Weos, u16* __restrict__ dst){
  int tid = blockIdx.x*256 + threadIdx.x;
  if (tid >= 8*38*512) return;
  int e = tid & 511, blk = tid >> 9;
  int lane = e >> 3, j = e & 7;
  int ns = blk / 38, kb = blk % 38;
  int q = lane >> 4, n = lane & 15;
  int k = kb*32 + q*8 + j;
  int col = ns*16 + n;
  float v = 0.f;
  if (k < 1200){
    if (col < 40)       v = Wmu[(size_t)col*1200 + k];
    else if (col < 80)  v = Wls[(size_t)(col-40)*1200 + k];
    else if (col < 100) v = Wrho[(size_t)(col-80)*1200 + k];
    else if (col < 120) v = Wpi[(size_t)(col-100)*1200 + k];
    else if (col == 120) v = Weos[k];
  }
  dst[tid] = f2bf(v);
}

// strokes rows + zero pads for all t (ws is 0xAA-poisoned every run)
__global__ void kfillA(P p){
  int tid = blockIdx.x*256 + threadIdx.x;
  if (tid >= 512*64*32) return;
  int it = tid & 31; int rr = tid >> 5; int b = rr & 63; int t = rr >> 6;
  const float* sx = p.strokes + ((size_t)t*64 + b)*3;
  if (it < 3)        p.A0[aidx(t,b,it,13)] = f2bf(sx[it]);
  else if (it < 16)  p.A0[aidx(t,b,400+it,13)] = 0;          // pads 403..415
  else if (it < 19)  p.A1[aidx(t,b,460+(it-16),27)] = f2bf(sx[it-16]);
  else if (it == 19) p.A1[aidx(t,b,863,27)] = 0;
  else if (it < 23)  p.A2[aidx(t,b,460+(it-20),27)] = f2bf(sx[it-20]);
  else if (it == 23) p.A2[aidx(t,b,863,27)] = 0;
}

// initial states + obuf/barrier zero
__global__ void kinit(P p){
  int tid = blockIdx.x*256 + threadIdx.x;
  if (tid < 25600){ int b=tid/400, j=tid%400; p.A0[aidx(0,b,3+j,13)] = f2bf(p.h0h[tid]); }
  else if (tid < 51200){ int i=tid-25600; int b=i/400, j=i%400; p.A1[aidx(0,b,463+j,27)] = f2bf(p.h1h[i]); }
  else if (tid < 76800){ int i=tid-51200; int b=i/400, j=i%400; p.A2[aidx(0,b,463+j,27)] = f2bf(p.h2h[i]); }
  else if (tid < 82560){ p.obuf[tid-76800] = 0.f; }
  else if (tid < 84992){ p.bar[tid-82560] = 0u; }
}

// ---------------- contention-free grid barrier ----------------
// Each WG release-stores its own padded flag (no cacheline bouncing).
// WG0 wave0: lane i polls flag i (75 parallel spins), then lane 0 publishes
// the generation word everyone else spins on. One acquire fence per WG after.
__device__ __forceinline__ void gsync(unsigned* bar, int wg, unsigned target){
  __syncthreads();
  const int tid = threadIdx.x;
  if (wg == 0){
    if (tid < 64){
      if (tid == 0)
        __hip_atomic_store(&bar[0], target, __ATOMIC_RELEASE, __HIP_MEMORY_SCOPE_AGENT);
      if (tid < 75){
        long c = 0;
        while (__hip_atomic_load(&bar[tid*32], __ATOMIC_RELAXED, __HIP_MEMORY_SCOPE_AGENT) < target){
          __builtin_amdgcn_s_sleep(1);
          if (++c > (1L<<25)) break;   // failsafe: wrong answer, never a hang
        }
      }
      if (tid == 0){
        __hip_atomic_store(&bar[GEN_IDX], target, __ATOMIC_RELEASE, __HIP_MEMORY_SCOPE_AGENT);
        __builtin_amdgcn_fence(__ATOMIC_ACQUIRE, "agent");
      }
    }
  } else {
    if (tid == 0){
      __hip_atomic_store(&bar[wg*32], target, __ATOMIC_RELEASE, __HIP_MEMORY_SCOPE_AGENT);
      long c = 0;
      while (__hip_atomic_load(&bar[GEN_IDX], __ATOMIC_RELAXED, __HIP_MEMORY_SCOPE_AGENT) < target){
        __builtin_amdgcn_s_sleep(1);
        if (++c > (1L<<25)) break;
      }
      __builtin_amdgcn_fence(__ATOMIC_ACQUIRE, "agent");
    }
  }
  __syncthreads();
}

// ---------------- gate GEMM: A from global (IC), B from LDS ----------------
template<int KB>
__device__ __forceinline__ void gate_gemm(const u16* __restrict__ Ap, const u16* wBl,
                                          int t, int lane, int wave, float4v* acc){
  const u16* Ab = Ap + ((size_t)(t*4 + wave)*KB)*512 + (size_t)lane*8;
  const u16* Bb = wBl + lane*8;
  #pragma unroll
  for (int kb = 0; kb < KB; ++kb){
    short8 af = *reinterpret_cast<const short8*>(Ab + (size_t)kb*512);
    #pragma unroll
    for (int tt = 0; tt < 4; ++tt){
      short8 bf = *reinterpret_cast<const short8*>(Bb + (size_t)(tt*KB + kb)*512);
      acc[tt] = __builtin_amdgcn_mfma_f32_16x16x32_bf16(af, bf, acc[tt], 0, 0, 0);
    }
  }
}

// ---------------- main persistent kernel: 75 WGs, 1 barrier/round ----------------
// grp0 (wg 0..24):  L0 at t=r   + window finalize w(r-1) + o-partials
// grp1 (wg 25..49): L1 at t=r-2
// grp2 (wg 50..74): L2 at t=r-3
// LDS: 110592 (weights / grp0 overlay) + 16640 gate tile + 4096 cell + 256 bias
__global__ __launch_bounds__(256, 1) void kmain(P p){
  const int wg = blockIdx.x, tid = threadIdx.x;
  const int lane = tid & 63, wave = tid >> 6;
  const int grp = (wg < 25) ? 0 : (wg < 50 ? 1 : 2);
  const int s = wg - grp*25;
  const int lag = (grp == 0) ? 0 : (grp + 1);   // 0,2,3

  __shared__ u16  wB[55296];         // 110592 B weight slice (+ grp0 overlay)
  __shared__ float ldsg[64][65];     // gate tile [b][4 tiles *16 cols]
  __shared__ float clds[16][64];     // persistent cell state [jj][b]
  __shared__ float bsum[64];         // bias sums [jj*4+gate], this slice

  // grp0 overlays in wB[30720..55295] (49152 B available, 46328 used)
  u16* wBw = wB + 26624;                                   // 8 KB inline-w weights
  char* exb = (char*)(wB + 30720);
  float (*hsh)[64]  = (float (*)[64])(exb);                //  4096 B  h0 stage
  float (*wacc)[64] = (float (*)[64])(exb + 4096);         // 15360 B  w accum
  u16   (*wbf)[80]  = (u16   (*)[80])(exb + 19456);        // 10240 B  w A-operand
  float (*klds)[10] = (float (*)[10])(exb + 29696);        //  2560 B  kappa
  float (*ash)[10]  = (float (*)[10])(exb + 32256);
  float (*bsh)[10]  = (float (*)[10])(exb + 34816);
  float (*ksh)[10]  = (float (*)[10])(exb + 37376);        // end 39936
  float (*wwin_l)[16] = (float (*)[16])(exb + 39936);      //  1920 B Wwin slice
  unsigned char* text_l = (unsigned char*)(exb + 41856);   //  4096 B text (u8)
  int*   tlen_l = (int*)(exb + 45952);                     //   256 B
  float* bwin_l = (float*)(exb + 46208);                   //   120 B, end 46328

  const u16 *Ap; u16 *yr;
  const float *bi, *bh, *cin; int ohh, occ;
  if (grp == 0){ Ap=p.A0; yr=p.y0; bi=p.bih0; bh=p.bhh0; cin=p.h0c; ohh=O_H0H; occ=O_H0C; }
  else if (grp == 1){ Ap=p.A1; yr=p.y1; bi=p.bih1; bh=p.bhh1; cin=p.h1c; ohh=O_H1H; occ=O_H1C; }
  else { Ap=p.A2; yr=p.y2; bi=p.bih2; bh=p.bhh2; cin=p.h2c; ohh=O_H2H; occ=O_H2C; }

  // ---- stage weight slice into LDS (once) ----
  {
    const u16* gsrc; int cnt;
    if (grp == 0){ gsrc = p.B0 + (size_t)s*26624; cnt = 26624; }
    else if (grp == 1){ gsrc = p.B1 + (size_t)s*55296; cnt = 55296; }
    else { gsrc = p.B2 + (size_t)s*55296; cnt = 55296; }
    for (int i = tid*8; i < cnt; i += 2048)
      *reinterpret_cast<short8*>(&wB[i]) = *reinterpret_cast<const short8*>(gsrc + i);
    if (grp == 0){
      const u16* gw = p.Bw0 + (size_t)s*4096;
      for (int i = tid*8; i < 4096; i += 2048)
        *reinterpret_cast<short8*>(wBw + i) = *reinterpret_cast<const short8*>(gw + i);
    }
  }

  for (int cell = tid; cell < 1024; cell += 256){
    int jj = cell >> 6, b = cell & 63;
    clds[jj][b] = cin[b*400 + s*16 + jj];
  }
  if (tid < 64){
    int jj = tid >> 2, gg = tid & 3;
    bsum[tid] = bi[gg*400 + s*16 + jj] + bh[gg*400 + s*16 + jj];
  }
  if (grp == 0){
    for (int cell = tid; cell < 640; cell += 256) klds[cell/10][cell%10] = p.pk[cell];
    for (int cell = tid; cell < 64*80; cell += 256){
      int b = cell/80, k = cell%80;
      wbf[b][k] = (k < 60) ? f2bf(p.pw[b*60 + k]) : (u16)0;
    }
    for (int cell = tid; cell < 480; cell += 256)
      wwin_l[cell>>4][cell&15] = p.Wwin[(cell>>4)*400 + s*16 + (cell&15)];
    for (int cell = tid; cell < 4096; cell += 256)
      text_l[cell] = (unsigned char)p.text[cell];
    if (tid < 64) tlen_l[tid] = p.tlen[tid];
    if (tid < 30) bwin_l[tid] = p.bwin[tid];
  }
  __syncthreads();

  for (int r = 0; r < 515; ++r){
    // ---- window finalize for t = r-1 (replicated across the 25 L0 WGs) ----
    if (grp == 0 && r >= 1 && r <= 512){
      const int tw = r - 1;
      const float* ob = p.obuf + (size_t)((r-1)%3)*1920;
      for (int cell = tid; cell < 1920; cell += 256){
        int b = cell & 63, n = cell >> 6;
        float o = ob[n*64 + b] + bwin_l[n];
        if (n < 10) ash[b][n] = __expf(o);
        else if (n < 20) bsh[b][n-10] = __expf(o);
        else { float kn = klds[b][n-20] + 0.05f*__expf(o); klds[b][n-20] = kn; ksh[b][n-20] = kn; }
      }
      for (int cell = tid; cell < 3840; cell += 256) ((float*)wacc)[cell] = 0.f;
      __syncthreads();
      for (int cell = tid; cell < 4096; cell += 256){
        int b = cell >> 6, u = cell & 63;
        float phi = 0.f;
        if (u < tlen_l[b]){
          #pragma unroll
          for (int n = 0; n < 10; ++n){
            float d = ksh[b][n] - (float)u;
            phi += ash[b][n]*__expf(-bsh[b][n]*d*d);
          }
          atomicAdd(&wacc[text_l[b*64 + u]][b], phi);
        }
        if (wg == 0) p.out[O_AL + ((size_t)tw*64 + b)*64 + u] = phi;
      }
      __syncthreads();
      for (int cell = tid; cell < 3840; cell += 256){
        int b = cell & 63, l = cell >> 6;
        u16 wv = f2bf(wacc[l][b]);
        wbf[b][l] = wv;
        if (wg == 1) p.A1[aidx(tw,b,400+l,27)] = wv;
        if (wg == 2) p.A2[aidx(tw,b,400+l,27)] = wv;
        if (wg == 0 && tw == 511) p.out[O_PW + b*60 + l] = wacc[l][b];
      }
      if (wg == 0 && tw == 511)
        for (int cell = tid; cell < 640; cell += 256) p.out[O_PK + cell] = klds[cell/10][cell%10];
      __syncthreads();
    }

    // ---- gate GEMM + LSTM pointwise ----
    const int t = r - lag;
    if (t >= 0 && t < 512){
      float4v acc[4] = {{0.f,0.f,0.f,0.f},{0.f,0.f,0.f,0.f},{0.f,0.f,0.f,0.f},{0.f,0.f,0.f,0.f}};
      if (grp == 0){
        gate_gemm<13>(Ap, wB, t, lane, wave, acc);
        const int m = lane & 15, q = (lane >> 4) & 3;
        #pragma unroll
        for (int kb = 0; kb < 2; ++kb){
          short8 af = *reinterpret_cast<const short8*>(&wbf[wave*16 + m][kb*32 + q*8]);
          #pragma unroll
          for (int tt = 0; tt < 4; ++tt){
            short8 bf = *reinterpret_cast<const short8*>(wBw + (size_t)((tt*2 + kb))*512 + (size_t)lane*8);
            acc[tt] = __builtin_amdgcn_mfma_f32_16x16x32_bf16(af, bf, acc[tt], 0, 0, 0);
          }
        }
      } else {
        gate_gemm<27>(Ap, wB, t, lane, wave, acc);
      }
      {
        const int c = lane & 15, rb = wave*16 + ((lane>>4)<<2);
        #pragma unroll
        for (int tt = 0; tt < 4; ++tt)
          #pragma unroll
          for (int rr2 = 0; rr2 < 4; ++rr2)
            ldsg[rb+rr2][tt*16 + c] = acc[tt][rr2];
      }
      __syncthreads();
      for (int cell = tid; cell < 1024; cell += 256){
        int jj = cell >> 6, b = cell & 63;
        int j = s*16 + jj, tt = jj >> 2, jo = jj & 3;
        float gi = ldsg[b][tt*16 +      jo] + bsum[jj*4 + 0];
        float gf = ldsg[b][tt*16 +  4 + jo] + bsum[jj*4 + 1];
        float gg = ldsg[b][tt*16 +  8 + jo] + bsum[jj*4 + 2];
        float go = ldsg[b][tt*16 + 12 + jo] + bsum[jj*4 + 3];
        float cp = clds[jj][b];
        float cn = sigm(gf)*cp + sigm(gi)*tanh_f(gg);
        float hh = sigm(go)*tanh_f(cn);
        clds[jj][b] = cn;
        u16 hb = f2bf(hh);
        yr[((size_t)t*64 + b)*400 + j] = hb;
        if (grp == 0){
          p.A1[aidx(t,b,j,27)] = hb;
          if (t < 511) p.A0[aidx(t+1,b,3+j,13)] = hb;
          hsh[jj][b] = hh;
        } else if (grp == 1){
          p.A2[aidx(t,b,j,27)] = hb;
          if (t < 511) p.A1[aidx(t+1,b,463+j,27)] = hb;
        } else {
          if (t < 511) p.A2[aidx(t+1,b,463+j,27)] = hb;
        }
        if (t == 511){ p.out[ohh + b*400 + j] = hh; p.out[occ + b*400 + j] = cn; }
      }
      if (grp == 0){
        __syncthreads();
        float* od = p.obuf + (size_t)(r%3)*1920;
        for (int cell = tid; cell < 1920; cell += 256){
          int b = cell & 63, n = cell >> 6;
          float sum = 0.f;
          #pragma unroll
          for (int jj = 0; jj < 16; ++jj)
            sum += hsh[jj][b] * wwin_l[n][jj];
          atomicAdd(&od[n*64 + b], sum);
        }
      }
    }
    // rotate-zero the o-slot that round r+1 will write
    if (wg == 50 && r <= 510){
      float* oz = p.obuf + (size_t)((r+1)%3)*1920;
      for (int cell = tid; cell < 1920; cell += 256) oz[cell] = 0.f;
    }
    if (r < 514) gsync(p.bar, wg, (unsigned)(r+1));
  }
}

// ---------------- output heads ----------------
__global__ __launch_bounds__(256) void kproj(P p){
  const int t = blockIdx.x >> 3, ns = blockIdx.x & 7;
  const int tid = threadIdx.x, lane = tid & 63, wave = tid >> 6;
  const int m = lane & 15, q = lane >> 4;
  float4v acc = {0.f,0.f,0.f,0.f};
  const size_t rowA = (size_t)t*64 + wave*16 + m;
  const u16* Bb = p.BP + ((size_t)ns*38)*512 + (size_t)lane*8;
  for (int kb = 0; kb < 38; ++kb){
    int k0 = kb*32 + q*8;
    const u16* src; int off;
    if (k0 < 400){ src = p.y0; off = k0; }
    else if (k0 < 800){ src = p.y1; off = k0 - 400; }
    else if (k0 < 1200){ src = p.y2; off = k0 - 800; }
    else { src = p.y0; off = 0; }     // B rows are zero for k>=1200
    short8 af = *reinterpret_cast<const short8*>(src + rowA*400 + off);
    short8 bf = *reinterpret_cast<const short8*>(Bb + (size_t)kb*512);
    acc = __builtin_amdgcn_mfma_f32_16x16x32_bf16(af, bf, acc, 0, 0, 0);
  }
  const int j = ns*16 + (lane & 15);
  const int bo = wave*16 + q*4;
  #pragma unroll
  for (int rr = 0; rr < 4; ++rr){
    float v = acc[rr];
    size_t ro = (size_t)t*64 + bo + rr;
    if (j < 40)        p.out[O_MEANS + ro*40 + j]        = v + p.bmu[j];
    else if (j < 80)   p.out[O_LS    + ro*40 + (j-40)]   = v + p.bls[j-40];
    else if (j < 100)  p.out[O_RHO   + ro*20 + (j-80)]   = tanhf(v + p.brho[j-80]);
    else if (j < 120)  p.out[O_PI    + ro*20 + (j-100)]  = v + p.bpi[j-100];
    else if (j == 120) p.out[O_EOS   + ro]               = v + p.beos[0];
  }
}

// ---------------- host ----------------
extern "C" void kernel_launch(void* const* d_in, const int* in_sizes, int n_in,
                              void* d_out, int out_size, void* d_ws, size_t ws_size,
                              hipStream_t stream){
  P p;
  p.strokes = (const float*)d_in[0];
  p.text    = (const int*)  d_in[1];
  p.tlen    = (const int*)  d_in[2];
  p.h0h = (const float*)d_in[3];  p.h0c = (const float*)d_in[4];
  p.h1h = (const float*)d_in[5];  p.h1c = (const float*)d_in[6];
  p.h2h = (const float*)d_in[7];  p.h2c = (const float*)d_in[8];
  p.pw  = (const float*)d_in[9];  p.pk  = (const float*)d_in[10];
  const float* Wih0 = (const float*)d_in[11]; const float* Whh0 = (const float*)d_in[12];
  p.bih0 = (const float*)d_in[13]; p.bhh0 = (const float*)d_in[14];
  const float* Wih1 = (const float*)d_in[15]; const float* Whh1 = (const float*)d_in[16];
  p.bih1 = (const float*)d_in[17]; p.bhh1 = (const float*)d_in[18];
  const float* Wih2 = (const float*)d_in[19]; const float* Whh2 = (const float*)d_in[20];
  p.bih2 = (const float*)d_in[21]; p.bhh2 = (const float*)d_in[22];
  p.Wwin = (const float*)d_in[23]; p.bwin = (const float*)d_in[24];
  const float* Wmu  = (const float*)d_in[25]; p.bmu  = (const float*)d_in[26];
  const float* Wls  = (const float*)d_in[27]; p.bls  = (const float*)d_in[28];
  const float* Wrho = (const float*)d_in[29]; p.brho = (const float*)d_in[30];
  const float* Wpi  = (const float*)d_in[31]; p.bpi  = (const float*)d_in[32];
  const float* Weos = (const float*)d_in[33]; p.beos = (const float*)d_in[34];
  p.out = (float*)d_out;

  char* w = (char*)d_ws; size_t off = 0;
  auto alloc = [&](size_t bytes)->void*{ void* r = w + off; off += (bytes + 511) & ~(size_t)511; return r; };
  p.B0  = (u16*)alloc((size_t)25*4*13*512*2);
  p.B1  = (u16*)alloc((size_t)25*4*27*512*2);
  p.B2  = (u16*)alloc((size_t)25*4*27*512*2);
  p.Bw0 = (u16*)alloc((size_t)25*4*2*512*2);
  p.BP  = (u16*)alloc((size_t)8*38*512*2);
  p.A0  = (u16*)alloc((size_t)512*4*13*512*2);
  p.A1  = (u16*)alloc((size_t)512*4*27*512*2);
  p.A2  = (u16*)alloc((size_t)512*4*27*512*2);
  p.y0  = (u16*)alloc((size_t)512*64*400*2);
  p.y1  = (u16*)alloc((size_t)512*64*400*2);
  p.y2  = (u16*)alloc((size_t)512*64*400*2);
  p.obuf= (float*)alloc((size_t)3*1920*4);
  p.bar = (unsigned*)alloc((size_t)2432*4);

  kpackB<<<dim3(2600), dim3(256), 0, stream>>>(Wih0, Whh0, p.B0, 13, 3,   63,  25*4*13*512);
  kpackB<<<dim3(5400), dim3(256), 0, stream>>>(Wih1, Whh1, p.B1, 27, 463, 463, 25*4*27*512);
  kpackB<<<dim3(5400), dim3(256), 0, stream>>>(Wih2, Whh2, p.B2, 27, 463, 463, 25*4*27*512);
  kpackBw<<<dim3(400), dim3(256), 0, stream>>>(Wih0, p.Bw0);
  kpackBP<<<dim3(608), dim3(256), 0, stream>>>(Wmu, Wls, Wrho, Wpi, Weos, p.BP);
  kfillA<<<dim3(4096), dim3(256), 0, stream>>>(p);
  kinit<<<dim3(332), dim3(256), 0, stream>>>(p);

  // plain launch: custom barrier needs no cooperative API; 75 WGs are
  // co-resident by construction (1 WG/CU min occupancy, 256 CUs).
  kmain<<<dim3(75), dim3(256), 0, stream>>>(p);

  kproj<<<dim3(4096), dim3(256), 0, stream>>>(p);
}

// Round 6
// 9867.488 us; speedup vs baseline: 4.1941x; 1.0388x over previous
//
#include <hip/hip_runtime.h>

typedef unsigned short u16;
typedef __attribute__((ext_vector_type(8))) short short8;   // 8 x bf16
typedef __attribute__((ext_vector_type(4))) float float4v;  // MFMA acc

// ---- output offsets (floats) ----
#define O_MEANS 0
#define O_LS    1310720
#define O_RHO   2621440
#define O_PI    3276800
#define O_EOS   3932160
#define O_H0H   3964928
#define O_H0C   3990528
#define O_H1H   4016128
#define O_H1C   4041728
#define O_H2H   4067328
#define O_H2C   4092928
#define O_PW    4118528
#define O_PK    4122368
#define O_AL    4123008

#define GEN_IDX 2400   // bar: [wg*32] arrival flags (128B apart), [2400] generation

struct P {
  const float *strokes; const int *text; const int *tlen;
  const float *h0h,*h0c,*h1h,*h1c,*h2h,*h2c,*pw,*pk;
  const float *bih0,*bhh0,*bih1,*bhh1,*bih2,*bhh2;
  const float *Wwin,*bwin;
  const float *bmu,*bls,*brho,*bpi,*beos;
  u16 *B0,*B1,*B2,*Bw0,*BP;     // fragment-packed weights
  u16 *A0,*A1,*A2;              // fragment-packed activations per step
  u16 *y0,*y1,*y2;              // bf16 row-major hidden histories [T][64][400]
  float *obuf;                  // 3 x [30][64] rotating o-partials (atomic-only access)
  unsigned *bar;                // padded arrival flags + gen
  float *out;
};

__device__ __forceinline__ u16 f2bf(float f){
  unsigned int x = __float_as_uint(f);
  unsigned int r = x + 0x7FFFu + ((x >> 16) & 1u);
  return (u16)(r >> 16);
}
// A-pack element (t, batch b, k) for a layer with KB k-blocks.
// block = (t*4 + b/16)*KB + k/32 ; inside: lane=((k>>3)&3)*16+(b&15), elem k&7
__device__ __forceinline__ size_t aidx(int t, int b, int k, int KB){
  return ((size_t)((t*4 + (b>>4))*KB + (k>>5)))*512
       + (size_t)(((((k>>3)&3)*16) + (b&15))*8 + (k&7));
}
__device__ __forceinline__ float sigm(float x){ return 1.f/(1.f+__expf(-x)); }
__device__ __forceinline__ float tanh_f(float x){ return 2.f/(1.f+__expf(-2.f*x)) - 1.f; }

// ---------------- weight packing ----------------
__global__ void kpackB(const float* __restrict__ Wih, const float* __restrict__ Whh,
                       u16* __restrict__ dst, int KB, int kx, int stride, int total){
  int tid = blockIdx.x*256 + threadIdx.x;
  if (tid >= total) return;
  int e = tid & 511, blk = tid >> 9;
  int kb = blk % KB, tile = (blk / KB) & 3, s = blk / (KB*4);
  int lane = e >> 3, j = e & 7;
  int q = lane >> 4, n = lane & 15;
  int k = kb*32 + q*8 + j;
  int col = s*16 + tile*4 + (n&3);
  int g = (n>>2)*400 + col;
  float v = 0.f;
  if (k < kx) v = Wih[(size_t)g*stride + k];
  else if (k < kx + 400) v = Whh[(size_t)g*400 + (k - kx)];
  dst[tid] = f2bf(v);
}

// inline-w weights for L0: [25][4][2][512], from Wih0 cols 3..62
__global__ void kpackBw(const float* __restrict__ Wih0, u16* __restrict__ dst){
  int tid = blockIdx.x*256 + threadIdx.x;
  if (tid >= 25*4*2*512) return;
  int e = tid & 511, blk = tid >> 9;
  int kb = blk & 1, tile = (blk>>1) & 3, s = blk >> 3;
  int lane = e >> 3, j = e & 7;
  int q = lane >> 4, n = lane & 15;
  int k = kb*32 + q*8 + j;
  int col = s*16 + tile*4 + (n&3);
  int g = (n>>2)*400 + col;
  dst[tid] = (k < 60) ? f2bf(Wih0[(size_t)g*63 + 3 + k]) : (u16)0;
}

// projection weights: cols 0..39 mu, 40..79 ls, 80..99 rho, 100..119 pi, 120 eos
__global__ void kpackBP(const float* __restrict__ Wmu, const float* __restrict__ Wls,
                        const float* __restrict__ Wrho, const float* __restrict__ Wpi,
                        const float* __restrict__ Weos, u16* __restrict__ dst){
  int tid = blockIdx.x*256 + threadIdx.x;
  if (tid >= 8*38*512) return;
  int e = tid & 511, blk = tid >> 9;
  int lane = e >> 3, j = e & 7;
  int ns = blk / 38, kb = blk % 38;
  int q = lane >> 4, n = lane & 15;
  int k = kb*32 + q*8 + j;
  int col = ns*16 + n;
  float v = 0.f;
  if (k < 1200){
    if (col < 40)       v = Wmu[(size_t)col*1200 + k];
    else if (col < 80)  v = Wls[(size_t)(col-40)*1200 + k];
    else if (col < 100) v = Wrho[(size_t)(col-80)*1200 + k];
    else if (col < 120) v = Wpi[(size_t)(col-100)*1200 + k];
    else if (col == 120) v = Weos[k];
  }
  dst[tid] = f2bf(v);
}

// strokes rows + zero pads for all t (ws is 0xAA-poisoned every run)
__global__ void kfillA(P p){
  int tid = blockIdx.x*256 + threadIdx.x;
  if (tid >= 512*64*32) return;
  int it = tid & 31; int rr = tid >> 5; int b = rr & 63; int t = rr >> 6;
  const float* sx = p.strokes + ((size_t)t*64 + b)*3;
  if (it < 3)        p.A0[aidx(t,b,it,13)] = f2bf(sx[it]);
  else if (it < 16)  p.A0[aidx(t,b,400+it,13)] = 0;          // pads 403..415
  else if (it < 19)  p.A1[aidx(t,b,460+(it-16),27)] = f2bf(sx[it-16]);
  else if (it == 19) p.A1[aidx(t,b,863,27)] = 0;
  else if (it < 23)  p.A2[aidx(t,b,460+(it-20),27)] = f2bf(sx[it-20]);
  else if (it == 23) p.A2[aidx(t,b,863,27)] = 0;
}

// initial states + obuf/barrier zero
__global__ void kinit(P p){
  int tid = blockIdx.x*256 + threadIdx.x;
  if (tid < 25600){ int b=tid/400, j=tid%400; p.A0[aidx(0,b,3+j,13)] = f2bf(p.h0h[tid]); }
  else if (tid < 51200){ int i=tid-25600; int b=i/400, j=i%400; p.A1[aidx(0,b,463+j,27)] = f2bf(p.h1h[i]); }
  else if (tid < 76800){ int i=tid-51200; int b=i/400, j=i%400; p.A2[aidx(0,b,463+j,27)] = f2bf(p.h2h[i]); }
  else if (tid < 82560){ p.obuf[tid-76800] = 0.f; }
  else if (tid < 84992){ p.bar[tid-82560] = 0u; }
}

// ---------------- grid barrier, no acquire fences ----------------
// Safe because all cross-WG plain-store data is write-once/read-once at fresh
// addresses (A-packs/y/out rotate per step; a reader's L2 never holds a stale
// copy of a line it has never touched). The only re-used shared object (obuf)
// is accessed exclusively with agent-scope atomics that bypass L2. Arrival
// stores keep RELEASE: the wbl2 pushes this round's dirty lines to IC.
__device__ __forceinline__ void gsync(unsigned* bar, int wg, unsigned target){
  __syncthreads();
  const int tid = threadIdx.x;
  if (wg == 0){
    if (tid < 75){
      if (tid == 0)
        __hip_atomic_store(&bar[0], target, __ATOMIC_RELEASE, __HIP_MEMORY_SCOPE_AGENT);
      long c = 0;
      while (__hip_atomic_load(&bar[tid*32], __ATOMIC_RELAXED, __HIP_MEMORY_SCOPE_AGENT) < target){
        __builtin_amdgcn_s_sleep(1);
        if (++c > (1L<<25)) break;   // failsafe: wrong answer, never a hang
      }
      if (tid == 0)
        __hip_atomic_store(&bar[GEN_IDX], target, __ATOMIC_RELAXED, __HIP_MEMORY_SCOPE_AGENT);
    }
  } else {
    if (tid == 0){
      __hip_atomic_store(&bar[wg*32], target, __ATOMIC_RELEASE, __HIP_MEMORY_SCOPE_AGENT);
      long c = 0;
      while (__hip_atomic_load(&bar[GEN_IDX], __ATOMIC_RELAXED, __HIP_MEMORY_SCOPE_AGENT) < target){
        __builtin_amdgcn_s_sleep(1);
        if (++c > (1L<<25)) break;
      }
    }
  }
  __syncthreads();
}

// ---------------- gate GEMM: A from global (IC), B from LDS ----------------
template<int KB>
__device__ __forceinline__ void gate_gemm(const u16* __restrict__ Ap, const u16* wBl,
                                          int t, int lane, int wave, float4v* acc){
  const u16* Ab = Ap + ((size_t)(t*4 + wave)*KB)*512 + (size_t)lane*8;
  const u16* Bb = wBl + lane*8;
  #pragma unroll
  for (int kb = 0; kb < KB; ++kb){
    short8 af = *reinterpret_cast<const short8*>(Ab + (size_t)kb*512);
    #pragma unroll
    for (int tt = 0; tt < 4; ++tt){
      short8 bf = *reinterpret_cast<const short8*>(Bb + (size_t)(tt*KB + kb)*512);
      acc[tt] = __builtin_amdgcn_mfma_f32_16x16x32_bf16(af, bf, acc[tt], 0, 0, 0);
    }
  }
}

// ---------------- main persistent kernel: 75 WGs, 1 barrier/round ----------------
// grp0 (wg 0..24):  L0 at t=r   + window finalize w(r-1) + o-partials
// grp1 (wg 25..49): L1 at t=r-2
// grp2 (wg 50..74): L2 at t=r-3
__global__ __launch_bounds__(256, 1) void kmain(P p){
  const int wg = blockIdx.x, tid = threadIdx.x;
  const int lane = tid & 63, wave = tid >> 6;
  const int grp = (wg < 25) ? 0 : (wg < 50 ? 1 : 2);
  const int s = wg - grp*25;
  const int lag = (grp == 0) ? 0 : (grp + 1);   // 0,2,3

  __shared__ u16  wB[55296];         // 110592 B weight slice (+ grp0 overlay)
  __shared__ float ldsg[64][65];     // gate tile [b][4 tiles *16 cols]
  __shared__ float clds[16][64];     // persistent cell state [jj][b]
  __shared__ float bsum[64];         // bias sums [jj*4+gate], this slice

  // grp0 overlays in wB[30720..55295] (49152 B available, 46328 used)
  u16* wBw = wB + 26624;                                   // 8 KB inline-w weights
  char* exb = (char*)(wB + 30720);
  float (*hsh)[64]  = (float (*)[64])(exb);                //  4096 B  h0 stage
  float (*wacc)[64] = (float (*)[64])(exb + 4096);         // 15360 B  w accum
  u16   (*wbf)[80]  = (u16   (*)[80])(exb + 19456);        // 10240 B  w A-operand
  float (*klds)[10] = (float (*)[10])(exb + 29696);        //  2560 B  kappa
  float (*ash)[10]  = (float (*)[10])(exb + 32256);
  float (*bsh)[10]  = (float (*)[10])(exb + 34816);
  float (*ksh)[10]  = (float (*)[10])(exb + 37376);        // end 39936
  float (*wwin_l)[16] = (float (*)[16])(exb + 39936);      //  1920 B Wwin slice
  unsigned char* text_l = (unsigned char*)(exb + 41856);   //  4096 B text (u8)
  int*   tlen_l = (int*)(exb + 45952);                     //   256 B
  float* bwin_l = (float*)(exb + 46208);                   //   120 B, end 46328

  const u16 *Ap; u16 *yr;
  const float *bi, *bh, *cin; int ohh, occ;
  if (grp == 0){ Ap=p.A0; yr=p.y0; bi=p.bih0; bh=p.bhh0; cin=p.h0c; ohh=O_H0H; occ=O_H0C; }
  else if (grp == 1){ Ap=p.A1; yr=p.y1; bi=p.bih1; bh=p.bhh1; cin=p.h1c; ohh=O_H1H; occ=O_H1C; }
  else { Ap=p.A2; yr=p.y2; bi=p.bih2; bh=p.bhh2; cin=p.h2c; ohh=O_H2H; occ=O_H2C; }

  // ---- stage weight slice into LDS (once) ----
  {
    const u16* gsrc; int cnt;
    if (grp == 0){ gsrc = p.B0 + (size_t)s*26624; cnt = 26624; }
    else if (grp == 1){ gsrc = p.B1 + (size_t)s*55296; cnt = 55296; }
    else { gsrc = p.B2 + (size_t)s*55296; cnt = 55296; }
    for (int i = tid*8; i < cnt; i += 2048)
      *reinterpret_cast<short8*>(&wB[i]) = *reinterpret_cast<const short8*>(gsrc + i);
    if (grp == 0){
      const u16* gw = p.Bw0 + (size_t)s*4096;
      for (int i = tid*8; i < 4096; i += 2048)
        *reinterpret_cast<short8*>(wBw + i) = *reinterpret_cast<const short8*>(gw + i);
    }
  }

  for (int cell = tid; cell < 1024; cell += 256){
    int jj = cell >> 6, b = cell & 63;
    clds[jj][b] = cin[b*400 + s*16 + jj];
  }
  if (tid < 64){
    int jj = tid >> 2, gg = tid & 3;
    bsum[tid] = bi[gg*400 + s*16 + jj] + bh[gg*400 + s*16 + jj];
  }
  if (grp == 0){
    for (int cell = tid; cell < 640; cell += 256) klds[cell/10][cell%10] = p.pk[cell];
    for (int cell = tid; cell < 64*80; cell += 256){
      int b = cell/80, k = cell%80;
      wbf[b][k] = (k < 60) ? f2bf(p.pw[b*60 + k]) : (u16)0;
    }
    for (int cell = tid; cell < 480; cell += 256)
      wwin_l[cell>>4][cell&15] = p.Wwin[(cell>>4)*400 + s*16 + (cell&15)];
    for (int cell = tid; cell < 4096; cell += 256)
      text_l[cell] = (unsigned char)p.text[cell];
    if (tid < 64) tlen_l[tid] = p.tlen[tid];
    if (tid < 30) bwin_l[tid] = p.bwin[tid];
  }
  __syncthreads();

  for (int r = 0; r < 515; ++r){
    const int t = r - lag;

    // ---- grp0: hoist A0 fragment loads (IC latency overlaps finalize) ----
    short8 a0r[13];
    if (grp == 0 && t < 512){
      const u16* Ab = p.A0 + ((size_t)(t*4 + wave)*13)*512 + (size_t)lane*8;
      #pragma unroll
      for (int kb = 0; kb < 13; ++kb)
        a0r[kb] = *reinterpret_cast<const short8*>(Ab + (size_t)kb*512);
    }

    // ---- window finalize for t = r-1 (replicated across the 25 L0 WGs) ----
    if (grp == 0 && r >= 1 && r <= 512){
      const int tw = r - 1;
      float* ob = p.obuf + (size_t)((r-1)%3)*1920;
      for (int cell = tid; cell < 1920; cell += 256){
        int b = cell & 63, n = cell >> 6;
        float o = __hip_atomic_load(&ob[n*64 + b], __ATOMIC_RELAXED, __HIP_MEMORY_SCOPE_AGENT)
                + bwin_l[n];
        if (n < 10) ash[b][n] = __expf(o);
        else if (n < 20) bsh[b][n-10] = __expf(o);
        else { float kn = klds[b][n-20] + 0.05f*__expf(o); klds[b][n-20] = kn; ksh[b][n-20] = kn; }
      }
      for (int cell = tid; cell < 3840; cell += 256) ((float*)wacc)[cell] = 0.f;
      __syncthreads();
      for (int cell = tid; cell < 4096; cell += 256){
        int b = cell >> 6, u = cell & 63;
        float phi = 0.f;
        if (u < tlen_l[b]){
          #pragma unroll
          for (int n = 0; n < 10; ++n){
            float d = ksh[b][n] - (float)u;
            phi += ash[b][n]*__expf(-bsh[b][n]*d*d);
          }
          atomicAdd(&wacc[text_l[b*64 + u]][b], phi);
        }
        if (wg == 4) p.out[O_AL + ((size_t)tw*64 + b)*64 + u] = phi;
      }
      __syncthreads();
      for (int cell = tid; cell < 3840; cell += 256){
        int b = cell & 63, l = cell >> 6;
        u16 wv = f2bf(wacc[l][b]);
        wbf[b][l] = wv;
        if (wg == 1) p.A1[aidx(tw,b,400+l,27)] = wv;
        if (wg == 2) p.A2[aidx(tw,b,400+l,27)] = wv;
        if (wg == 0 && tw == 511) p.out[O_PW + b*60 + l] = wacc[l][b];
      }
      if (wg == 0 && tw == 511)
        for (int cell = tid; cell < 640; cell += 256) p.out[O_PK + cell] = klds[cell/10][cell%10];
      __syncthreads();
    }

    // ---- gate GEMM + LSTM pointwise ----
    if (t >= 0 && t < 512){
      float4v acc[4] = {{0.f,0.f,0.f,0.f},{0.f,0.f,0.f,0.f},{0.f,0.f,0.f,0.f},{0.f,0.f,0.f,0.f}};
      if (grp == 0){
        #pragma unroll
        for (int kb = 0; kb < 13; ++kb){
          #pragma unroll
          for (int tt = 0; tt < 4; ++tt){
            short8 bf = *reinterpret_cast<const short8*>(wB + (size_t)(tt*13 + kb)*512 + (size_t)lane*8);
            acc[tt] = __builtin_amdgcn_mfma_f32_16x16x32_bf16(a0r[kb], bf, acc[tt], 0, 0, 0);
          }
        }
        const int m = lane & 15, q = (lane >> 4) & 3;
        #pragma unroll
        for (int kb = 0; kb < 2; ++kb){
          short8 af = *reinterpret_cast<const short8*>(&wbf[wave*16 + m][kb*32 + q*8]);
          #pragma unroll
          for (int tt = 0; tt < 4; ++tt){
            short8 bf = *reinterpret_cast<const short8*>(wBw + (size_t)((tt*2 + kb))*512 + (size_t)lane*8);
            acc[tt] = __builtin_amdgcn_mfma_f32_16x16x32_bf16(af, bf, acc[tt], 0, 0, 0);
          }
        }
      } else {
        gate_gemm<27>(Ap, wB, t, lane, wave, acc);
      }
      {
        const int c = lane & 15, rb = wave*16 + ((lane>>4)<<2);
        #pragma unroll
        for (int tt = 0; tt < 4; ++tt)
          #pragma unroll
          for (int rr2 = 0; rr2 < 4; ++rr2)
            ldsg[rb+rr2][tt*16 + c] = acc[tt][rr2];
      }
      __syncthreads();
      for (int cell = tid; cell < 1024; cell += 256){
        int jj = cell >> 6, b = cell & 63;
        int j = s*16 + jj, tt = jj >> 2, jo = jj & 3;
        float gi = ldsg[b][tt*16 +      jo] + bsum[jj*4 + 0];
        float gf = ldsg[b][tt*16 +  4 + jo] + bsum[jj*4 + 1];
        float gg = ldsg[b][tt*16 +  8 + jo] + bsum[jj*4 + 2];
        float go = ldsg[b][tt*16 + 12 + jo] + bsum[jj*4 + 3];
        float cp = clds[jj][b];
        float cn = sigm(gf)*cp + sigm(gi)*tanh_f(gg);
        float hh = sigm(go)*tanh_f(cn);
        clds[jj][b] = cn;
        u16 hb = f2bf(hh);
        yr[((size_t)t*64 + b)*400 + j] = hb;
        if (grp == 0){
          p.A1[aidx(t,b,j,27)] = hb;
          if (t < 511) p.A0[aidx(t+1,b,3+j,13)] = hb;
          hsh[jj][b] = hh;
        } else if (grp == 1){
          p.A2[aidx(t,b,j,27)] = hb;
          if (t < 511) p.A1[aidx(t+1,b,463+j,27)] = hb;
        } else {
          if (t < 511) p.A2[aidx(t+1,b,463+j,27)] = hb;
        }
        if (t == 511){ p.out[ohh + b*400 + j] = hh; p.out[occ + b*400 + j] = cn; }
      }
      if (grp == 0){
        __syncthreads();
        float* od = p.obuf + (size_t)(r%3)*1920;
        for (int cell = tid; cell < 1920; cell += 256){
          int b = cell & 63, n = cell >> 6;
          float sum = 0.f;
          #pragma unroll
          for (int jj = 0; jj < 16; ++jj)
            sum += hsh[jj][b] * wwin_l[n][jj];
          atomicAdd(&od[n*64 + b], sum);
        }
      }
    }
    // rotate-zero the o-slot that round r+1 will write (atomic: obuf lines recycle)
    if (wg == 50 && r <= 510){
      float* oz = p.obuf + (size_t)((r+1)%3)*1920;
      for (int cell = tid; cell < 1920; cell += 256)
        __hip_atomic_store(&oz[cell], 0.f, __ATOMIC_RELAXED, __HIP_MEMORY_SCOPE_AGENT);
    }
    if (r < 514) gsync(p.bar, wg, (unsigned)(r+1));
  }
}

// ---------------- output heads ----------------
__global__ __launch_bounds__(256) void kproj(P p){
  const int t = blockIdx.x >> 3, ns = blockIdx.x & 7;
  const int tid = threadIdx.x, lane = tid & 63, wave = tid >> 6;
  const int m = lane & 15, q = lane >> 4;
  float4v acc = {0.f,0.f,0.f,0.f};
  const size_t rowA = (size_t)t*64 + wave*16 + m;
  const u16* Bb = p.BP + ((size_t)ns*38)*512 + (size_t)lane*8;
  for (int kb = 0; kb < 38; ++kb){
    int k0 = kb*32 + q*8;
    const u16* src; int off;
    if (k0 < 400){ src = p.y0; off = k0; }
    else if (k0 < 800){ src = p.y1; off = k0 - 400; }
    else if (k0 < 1200){ src = p.y2; off = k0 - 800; }
    else { src = p.y0; off = 0; }     // B rows are zero for k>=1200
    short8 af = *reinterpret_cast<const short8*>(src + rowA*400 + off);
    short8 bf = *reinterpret_cast<const short8*>(Bb + (size_t)kb*512);
    acc = __builtin_amdgcn_mfma_f32_16x16x32_bf16(af, bf, acc, 0, 0, 0);
  }
  const int j = ns*16 + (lane & 15);
  const int bo = wave*16 + q*4;
  #pragma unroll
  for (int rr = 0; rr < 4; ++rr){
    float v = acc[rr];
    size_t ro = (size_t)t*64 + bo + rr;
    if (j < 40)        p.out[O_MEANS + ro*40 + j]        = v + p.bmu[j];
    else if (j < 80)   p.out[O_LS    + ro*40 + (j-40)]   = v + p.bls[j-40];
    else if (j < 100)  p.out[O_RHO   + ro*20 + (j-80)]   = tanhf(v + p.brho[j-80]);
    else if (j < 120)  p.out[O_PI    + ro*20 + (j-100)]  = v + p.bpi[j-100];
    else if (j == 120) p.out[O_EOS   + ro]               = v + p.beos[0];
  }
}

// ---------------- host ----------------
extern "C" void kernel_launch(void* const* d_in, const int* in_sizes, int n_in,
                              void* d_out, int out_size, void* d_ws, size_t ws_size,
                              hipStream_t stream){
  P p;
  p.strokes = (const float*)d_in[0];
  p.text    = (const int*)  d_in[1];
  p.tlen    = (const int*)  d_in[2];
  p.h0h = (const float*)d_in[3];  p.h0c = (const float*)d_in[4];
  p.h1h = (const float*)d_in[5];  p.h1c = (const float*)d_in[6];
  p.h2h = (const float*)d_in[7];  p.h2c = (const float*)d_in[8];
  p.pw  = (const float*)d_in[9];  p.pk  = (const float*)d_in[10];
  const float* Wih0 = (const float*)d_in[11]; const float* Whh0 = (const float*)d_in[12];
  p.bih0 = (const float*)d_in[13]; p.bhh0 = (const float*)d_in[14];
  const float* Wih1 = (const float*)d_in[15]; const float* Whh1 = (const float*)d_in[16];
  p.bih1 = (const float*)d_in[17]; p.bhh1 = (const float*)d_in[18];
  const float* Wih2 = (const float*)d_in[19]; const float* Whh2 = (const float*)d_in[20];
  p.bih2 = (const float*)d_in[21]; p.bhh2 = (const float*)d_in[22];
  p.Wwin = (const float*)d_in[23]; p.bwin = (const float*)d_in[24];
  const float* Wmu  = (const float*)d_in[25]; p.bmu  = (const float*)d_in[26];
  const float* Wls  = (const float*)d_in[27]; p.bls  = (const float*)d_in[28];
  const float* Wrho = (const float*)d_in[29]; p.brho = (const float*)d_in[30];
  const float* Wpi  = (const float*)d_in[31]; p.bpi  = (const float*)d_in[32];
  const float* Weos = (const float*)d_in[33]; p.beos = (const float*)d_in[34];
  p.out = (float*)d_out;

  char* w = (char*)d_ws; size_t off = 0;
  auto alloc = [&](size_t bytes)->void*{ void* r = w + off; off += (bytes + 511) & ~(size_t)511; return r; };
  p.B0  = (u16*)alloc((size_t)25*4*13*512*2);
  p.B1  = (u16*)alloc((size_t)25*4*27*512*2);
  p.B2  = (u16*)alloc((size_t)25*4*27*512*2);
  p.Bw0 = (u16*)alloc((size_t)25*4*2*512*2);
  p.BP  = (u16*)alloc((size_t)8*38*512*2);
  p.A0  = (u16*)alloc((size_t)512*4*13*512*2);
  p.A1  = (u16*)alloc((size_t)512*4*27*512*2);
  p.A2  = (u16*)alloc((size_t)512*4*27*512*2);
  p.y0  = (u16*)alloc((size_t)512*64*400*2);
  p.y1  = (u16*)alloc((size_t)512*64*400*2);
  p.y2  = (u16*)alloc((size_t)512*64*400*2);
  p.obuf= (float*)alloc((size_t)3*1920*4);
  p.bar = (unsigned*)alloc((size_t)2432*4);

  kpackB<<<dim3(2600), dim3(256), 0, stream>>>(Wih0, Whh0, p.B0, 13, 3,   63,  25*4*13*512);
  kpackB<<<dim3(5400), dim3(256), 0, stream>>>(Wih1, Whh1, p.B1, 27, 463, 463, 25*4*27*512);
  kpackB<<<dim3(5400), dim3(256), 0, stream>>>(Wih2, Whh2, p.B2, 27, 463, 463, 25*4*27*512);
  kpackBw<<<dim3(400), dim3(256), 0, stream>>>(Wih0, p.Bw0);
  kpackBP<<<dim3(608), dim3(256), 0, stream>>>(Wmu, Wls, Wrho, Wpi, Weos, p.BP);
  kfillA<<<dim3(4096), dim3(256), 0, stream>>>(p);
  kinit<<<dim3(332), dim3(256), 0, stream>>>(p);

  // plain launch: custom barrier needs no cooperative API; 75 WGs are
  // co-resident by construction (1 WG/CU min occupancy, 256 CUs).
  kmain<<<dim3(75), dim3(256), 0, stream>>>(p);

  kproj<<<dim3(4096), dim3(256), 0, stream>>>(p);
}

// Round 8
// 9130.419 us; speedup vs baseline: 4.5327x; 1.0807x over previous
//
#include <hip/hip_runtime.h>

typedef unsigned short u16;
typedef __attribute__((ext_vector_type(8))) short short8;   // 8 x bf16
typedef __attribute__((ext_vector_type(4))) float float4v;  // MFMA acc

// ---- output offsets (floats) ----
#define O_MEANS 0
#define O_LS    1310720
#define O_RHO   2621440
#define O_PI    3276800
#define O_EOS   3932160
#define O_H0H   3964928
#define O_H0C   3990528
#define O_H1H   4016128
#define O_H1C   4041728
#define O_H2H   4067328
#define O_H2C   4092928
#define O_PW    4118528
#define O_PK    4122368
#define O_AL    4123008

#define GEN_IDX 2400   // bar: [wg*32] arrival flags (128B apart), [2400] generation

struct P {
  const float *strokes; const int *text; const int *tlen;
  const float *h0h,*h0c,*h1h,*h1c,*h2h,*h2c,*pw,*pk;
  const float *bih0,*bhh0,*bih1,*bhh1,*bih2,*bhh2;
  const float *Wwin,*bwin;
  const float *bmu,*bls,*brho,*bpi,*beos;
  u16 *B0,*B1,*B2,*Bw0,*BP;     // fragment-packed weights
  u16 *A0,*A1,*A2;              // fragment-packed activations per step
  u16 *y0,*y1,*y2;              // bf16 row-major hidden histories [T][64][400]
  float *obuf;                  // 3 rounds x 5 banks x [30][64] o-partials (atomic-only)
  unsigned *bar;                // padded arrival flags + gen
  float *out;
};

__device__ __forceinline__ u16 f2bf(float f){
  unsigned int x = __float_as_uint(f);
  unsigned int r = x + 0x7FFFu + ((x >> 16) & 1u);
  return (u16)(r >> 16);
}
// A-pack element (t, batch b, k) for a layer with KB k-blocks.
// block = (t*4 + b/16)*KB + k/32 ; inside: lane=((k>>3)&3)*16+(b&15), elem k&7
__device__ __forceinline__ size_t aidx(int t, int b, int k, int KB){
  return ((size_t)((t*4 + (b>>4))*KB + (k>>5)))*512
       + (size_t)(((((k>>3)&3)*16) + (b&15))*8 + (k&7));
}
__device__ __forceinline__ float sigm(float x){ return 1.f/(1.f+__expf(-x)); }
__device__ __forceinline__ float tanh_f(float x){ return 2.f/(1.f+__expf(-2.f*x)) - 1.f; }

// ---------------- weight packing ----------------
__global__ void kpackB(const float* __restrict__ Wih, const float* __restrict__ Whh,
                       u16* __restrict__ dst, int KB, int kx, int stride, int total){
  int tid = blockIdx.x*256 + threadIdx.x;
  if (tid >= total) return;
  int e = tid & 511, blk = tid >> 9;
  int kb = blk % KB, tile = (blk / KB) & 3, s = blk / (KB*4);
  int lane = e >> 3, j = e & 7;
  int q = lane >> 4, n = lane & 15;
  int k = kb*32 + q*8 + j;
  int col = s*16 + tile*4 + (n&3);
  int g = (n>>2)*400 + col;
  float v = 0.f;
  if (k < kx) v = Wih[(size_t)g*stride + k];
  else if (k < kx + 400) v = Whh[(size_t)g*400 + (k - kx)];
  dst[tid] = f2bf(v);
}

// inline-w weights for L0: [25][4][2][512], from Wih0 cols 3..62
__global__ void kpackBw(const float* __restrict__ Wih0, u16* __restrict__ dst){
  int tid = blockIdx.x*256 + threadIdx.x;
  if (tid >= 25*4*2*512) return;
  int e = tid & 511, blk = tid >> 9;
  int kb = blk & 1, tile = (blk>>1) & 3, s = blk >> 3;
  int lane = e >> 3, j = e & 7;
  int q = lane >> 4, n = lane & 15;
  int k = kb*32 + q*8 + j;
  int col = s*16 + tile*4 + (n&3);
  int g = (n>>2)*400 + col;
  dst[tid] = (k < 60) ? f2bf(Wih0[(size_t)g*63 + 3 + k]) : (u16)0;
}

// projection weights: cols 0..39 mu, 40..79 ls, 80..99 rho, 100..119 pi, 120 eos
__global__ void kpackBP(const float* __restrict__ Wmu, const float* __restrict__ Wls,
                        const float* __restrict__ Wrho, const float* __restrict__ Wpi,
                        const float* __restrict__ Weos, u16* __restrict__ dst){
  int tid = blockIdx.x*256 + threadIdx.x;
  if (tid >= 8*38*512) return;
  int e = tid & 511, blk = tid >> 9;
  int lane = e >> 3, j = e & 7;
  int ns = blk / 38, kb = blk % 38;
  int q = lane >> 4, n = lane & 15;
  int k = kb*32 + q*8 + j;
  int col = ns*16 + n;
  float v = 0.f;
  if (k < 1200){
    if (col < 40)       v = Wmu[(size_t)col*1200 + k];
    else if (col < 80)  v = Wls[(size_t)(col-40)*1200 + k];
    else if (col < 100) v = Wrho[(size_t)(col-80)*1200 + k];
    else if (col < 120) v = Wpi[(size_t)(col-100)*1200 + k];
    else if (col == 120) v = Weos[k];
  }
  dst[tid] = f2bf(v);
}

// strokes rows + zero pads for all t (ws is 0xAA-poisoned every run)
__global__ void kfillA(P p){
  int tid = blockIdx.x*256 + threadIdx.x;
  if (tid >= 512*64*32) return;
  int it = tid & 31; int rr = tid >> 5; int b = rr & 63; int t = rr >> 6;
  const float* sx = p.strokes + ((size_t)t*64 + b)*3;
  if (it < 3)        p.A0[aidx(t,b,it,13)] = f2bf(sx[it]);
  else if (it < 16)  p.A0[aidx(t,b,400+it,13)] = 0;          // pads 403..415
  else if (it < 19)  p.A1[aidx(t,b,460+(it-16),27)] = f2bf(sx[it-16]);
  else if (it == 19) p.A1[aidx(t,b,863,27)] = 0;
  else if (it < 23)  p.A2[aidx(t,b,460+(it-20),27)] = f2bf(sx[it-20]);
  else if (it == 23) p.A2[aidx(t,b,863,27)] = 0;
}

// initial states + obuf/barrier zero
__global__ void kinit(P p){
  int tid = blockIdx.x*256 + threadIdx.x;
  if (tid < 25600){ int b=tid/400, j=tid%400; p.A0[aidx(0,b,3+j,13)] = f2bf(p.h0h[tid]); }
  else if (tid < 51200){ int i=tid-25600; int b=i/400, j=i%400; p.A1[aidx(0,b,463+j,27)] = f2bf(p.h1h[i]); }
  else if (tid < 76800){ int i=tid-51200; int b=i/400, j=i%400; p.A2[aidx(0,b,463+j,27)] = f2bf(p.h2h[i]); }
  else if (tid < 105600){ p.obuf[tid-76800] = 0.f; }
  else if (tid < 108032){ p.bar[tid-105600] = 0u; }
}

// ---------------- grid barrier (R6 topology + gen-publish race fix) ----------------
// No acquire fences: all cross-WG plain-store data is write-once/read-once at
// fresh addresses; the one recycled object (obuf) is atomic-only. Arrival keeps
// RELEASE (wbl2 pushes this round's dirty lines to IC). WG0 publishes the
// generation only after the WHOLE WG (both polling waves) confirms all 75
// arrivals — fixes R6's wave1 race.
__device__ __forceinline__ void gsync(unsigned* bar, int wg, unsigned target){
  __syncthreads();
  const int tid = threadIdx.x;
  if (wg == 0){
    if (tid == 0)
      __hip_atomic_store(&bar[0], target, __ATOMIC_RELEASE, __HIP_MEMORY_SCOPE_AGENT);
    if (tid < 75){
      long c = 0;
      while (__hip_atomic_load(&bar[tid*32], __ATOMIC_RELAXED, __HIP_MEMORY_SCOPE_AGENT) < target){
        __builtin_amdgcn_s_sleep(1);
        if (++c > (1L<<25)) break;   // failsafe: wrong answer, never a hang
      }
    }
    __syncthreads();   // all 75 arrivals confirmed by both polling waves
    if (tid == 0)
      __hip_atomic_store(&bar[GEN_IDX], target, __ATOMIC_RELAXED, __HIP_MEMORY_SCOPE_AGENT);
  } else {
    if (tid == 0){
      __hip_atomic_store(&bar[wg*32], target, __ATOMIC_RELEASE, __HIP_MEMORY_SCOPE_AGENT);
      long c = 0;
      while (__hip_atomic_load(&bar[GEN_IDX], __ATOMIC_RELAXED, __HIP_MEMORY_SCOPE_AGENT) < target){
        __builtin_amdgcn_s_sleep(1);
        if (++c > (1L<<25)) break;
      }
    }
  }
  __syncthreads();
}

// ---------------- gate GEMM: A from global (IC), B from LDS ----------------
template<int KB>
__device__ __forceinline__ void gate_gemm(const u16* __restrict__ Ap, const u16* wBl,
                                          int t, int lane, int wave, float4v* acc){
  const u16* Ab = Ap + ((size_t)(t*4 + wave)*KB)*512 + (size_t)lane*8;
  const u16* Bb = wBl + lane*8;
  #pragma unroll
  for (int kb = 0; kb < KB; ++kb){
    short8 af = *reinterpret_cast<const short8*>(Ab + (size_t)kb*512);
    #pragma unroll
    for (int tt = 0; tt < 4; ++tt){
      short8 bf = *reinterpret_cast<const short8*>(Bb + (size_t)(tt*KB + kb)*512);
      acc[tt] = __builtin_amdgcn_mfma_f32_16x16x32_bf16(af, bf, acc[tt], 0, 0, 0);
    }
  }
}

// ---------------- main persistent kernel: 75 WGs, 1 barrier/round ----------------
// grp0 (wg 0..24):  L0 at t=r   + window finalize w(r-1) + o-partials
// grp1 (wg 25..49): L1 at t=r-2
// grp2 (wg 50..74): L2 at t=r-3 + spread obuf zeroing
__global__ __launch_bounds__(256, 1) void kmain(P p){
  const int wg = blockIdx.x, tid = threadIdx.x;
  const int lane = tid & 63, wave = tid >> 6;
  const int grp = (wg < 25) ? 0 : (wg < 50 ? 1 : 2);
  const int s = wg - grp*25;
  const int lag = (grp == 0) ? 0 : (grp + 1);   // 0,2,3

  __shared__ u16  wB[55296];         // 110592 B weight slice (+ grp0 overlay)
  __shared__ float ldsg[64][65];     // gate tile [b][4 tiles *16 cols]
  __shared__ float clds[16][64];     // persistent cell state [jj][b]
  __shared__ float bsum[64];         // bias sums [jj*4+gate], this slice

  // grp0 overlays in wB[30720..55295] (49152 B available, 46328 used)
  u16* wBw = wB + 26624;                                   // 8 KB inline-w weights
  char* exb = (char*)(wB + 30720);
  float (*hsh)[64]  = (float (*)[64])(exb);                //  4096 B  h0 stage
  float (*wacc)[64] = (float (*)[64])(exb + 4096);         // 15360 B  w accum
  u16   (*wbf)[80]  = (u16   (*)[80])(exb + 19456);        // 10240 B  w A-operand
  float (*klds)[10] = (float (*)[10])(exb + 29696);        //  2560 B  kappa
  float (*ash)[10]  = (float (*)[10])(exb + 32256);
  float (*bsh)[10]  = (float (*)[10])(exb + 34816);
  float (*ksh)[10]  = (float (*)[10])(exb + 37376);        // end 39936
  float (*wwin_l)[16] = (float (*)[16])(exb + 39936);      //  1920 B Wwin slice
  unsigned char* text_l = (unsigned char*)(exb + 41856);   //  4096 B text (u8)
  int*   tlen_l = (int*)(exb + 45952);                     //   256 B
  float* bwin_l = (float*)(exb + 46208);                   //   120 B, end 46328

  const u16 *Ap; u16 *yr;
  const float *bi, *bh, *cin; int ohh, occ;
  if (grp == 0){ Ap=p.A0; yr=p.y0; bi=p.bih0; bh=p.bhh0; cin=p.h0c; ohh=O_H0H; occ=O_H0C; }
  else if (grp == 1){ Ap=p.A1; yr=p.y1; bi=p.bih1; bh=p.bhh1; cin=p.h1c; ohh=O_H1H; occ=O_H1C; }
  else { Ap=p.A2; yr=p.y2; bi=p.bih2; bh=p.bhh2; cin=p.h2c; ohh=O_H2H; occ=O_H2C; }

  // ---- stage weight slice into LDS (once) ----
  {
    const u16* gsrc; int cnt;
    if (grp == 0){ gsrc = p.B0 + (size_t)s*26624; cnt = 26624; }
    else if (grp == 1){ gsrc = p.B1 + (size_t)s*55296; cnt = 55296; }
    else { gsrc = p.B2 + (size_t)s*55296; cnt = 55296; }
    for (int i = tid*8; i < cnt; i += 2048)
      *reinterpret_cast<short8*>(&wB[i]) = *reinterpret_cast<const short8*>(gsrc + i);
    if (grp == 0){
      const u16* gw = p.Bw0 + (size_t)s*4096;
      for (int i = tid*8; i < 4096; i += 2048)
        *reinterpret_cast<short8*>(wBw + i) = *reinterpret_cast<const short8*>(gw + i);
    }
  }

  for (int cell = tid; cell < 1024; cell += 256){
    int jj = cell >> 6, b = cell & 63;
    clds[jj][b] = cin[b*400 + s*16 + jj];
  }
  if (tid < 64){
    int jj = tid >> 2, gg = tid & 3;
    bsum[tid] = bi[gg*400 + s*16 + jj] + bh[gg*400 + s*16 + jj];
  }
  if (grp == 0){
    for (int cell = tid; cell < 640; cell += 256) klds[cell/10][cell%10] = p.pk[cell];
    for (int cell = tid; cell < 64*80; cell += 256){
      int b = cell/80, k = cell%80;
      wbf[b][k] = (k < 60) ? f2bf(p.pw[b*60 + k]) : (u16)0;
    }
    for (int cell = tid; cell < 480; cell += 256)
      wwin_l[cell>>4][cell&15] = p.Wwin[(cell>>4)*400 + s*16 + (cell&15)];
    for (int cell = tid; cell < 4096; cell += 256)
      text_l[cell] = (unsigned char)p.text[cell];
    if (tid < 64) tlen_l[tid] = p.tlen[tid];
    if (tid < 30) bwin_l[tid] = p.bwin[tid];
  }
  __syncthreads();

  for (int r = 0; r < 515; ++r){
    const int t = r - lag;

    // ---- grp0: hoist obuf bank loads (5-bank, /5 contention) then A0 frags ----
    float ovs[8][5];
    if (grp == 0 && r >= 1 && r <= 512){
      const float* ob = p.obuf + (size_t)((r-1)%3)*9600;
      #pragma unroll
      for (int i = 0; i < 8; ++i){
        int cell = tid + i*256;
        if (cell < 1920){
          #pragma unroll
          for (int bk = 0; bk < 5; ++bk)
            ovs[i][bk] = __hip_atomic_load(&ob[bk*1920 + cell], __ATOMIC_RELAXED, __HIP_MEMORY_SCOPE_AGENT);
        }
      }
    }
    short8 a0r[13];
    if (grp == 0 && t < 512){
      const u16* Ab = p.A0 + ((size_t)(t*4 + wave)*13)*512 + (size_t)lane*8;
      #pragma unroll
      for (int kb = 0; kb < 13; ++kb)
        a0r[kb] = *reinterpret_cast<const short8*>(Ab + (size_t)kb*512);
    }

    // ---- window finalize for t = r-1 (replicated across the 25 L0 WGs) ----
    if (grp == 0 && r >= 1 && r <= 512){
      const int tw = r - 1;
      #pragma unroll
      for (int i = 0; i < 8; ++i){
        int cell = tid + i*256;
        if (cell < 1920){
          int b = cell & 63, n = cell >> 6;
          float o = ovs[i][0]+ovs[i][1]+ovs[i][2]+ovs[i][3]+ovs[i][4] + bwin_l[n];
          if (n < 10) ash[b][n] = __expf(o);
          else if (n < 20) bsh[b][n-10] = __expf(o);
          else { float kn = klds[b][n-20] + 0.05f*__expf(o); klds[b][n-20] = kn; ksh[b][n-20] = kn; }
        }
      }
      for (int cell = tid; cell < 3840; cell += 256) ((float*)wacc)[cell] = 0.f;
      __syncthreads();
      for (int cell = tid; cell < 4096; cell += 256){
        int b = cell >> 6, u = cell & 63;
        float phi = 0.f;
        if (u < tlen_l[b]){
          #pragma unroll
          for (int n = 0; n < 10; ++n){
            float d = ksh[b][n] - (float)u;
            phi += ash[b][n]*__expf(-bsh[b][n]*d*d);
          }
          atomicAdd(&wacc[text_l[b*64 + u]][b], phi);
        }
        if (wg == 4) p.out[O_AL + ((size_t)tw*64 + b)*64 + u] = phi;
      }
      __syncthreads();
      for (int cell = tid; cell < 3840; cell += 256){
        int b = cell & 63, l = cell >> 6;
        u16 wv = f2bf(wacc[l][b]);
        wbf[b][l] = wv;
        if (wg == 1) p.A1[aidx(tw,b,400+l,27)] = wv;
        if (wg == 2) p.A2[aidx(tw,b,400+l,27)] = wv;
        if (wg == 0 && tw == 511) p.out[O_PW + b*60 + l] = wacc[l][b];
      }
      if (wg == 0 && tw == 511)
        for (int cell = tid; cell < 640; cell += 256) p.out[O_PK + cell] = klds[cell/10][cell%10];
      __syncthreads();
    }

    // ---- gate GEMM + LSTM pointwise ----
    if (t >= 0 && t < 512){
      float4v acc[4] = {{0.f,0.f,0.f,0.f},{0.f,0.f,0.f,0.f},{0.f,0.f,0.f,0.f},{0.f,0.f,0.f,0.f}};
      if (grp == 0){
        #pragma unroll
        for (int kb = 0; kb < 13; ++kb){
          #pragma unroll
          for (int tt = 0; tt < 4; ++tt){
            short8 bf = *reinterpret_cast<const short8*>(wB + (size_t)(tt*13 + kb)*512 + (size_t)lane*8);
            acc[tt] = __builtin_amdgcn_mfma_f32_16x16x32_bf16(a0r[kb], bf, acc[tt], 0, 0, 0);
          }
        }
        const int m = lane & 15, q = (lane >> 4) & 3;
        #pragma unroll
        for (int kb = 0; kb < 2; ++kb){
          short8 af = *reinterpret_cast<const short8*>(&wbf[wave*16 + m][kb*32 + q*8]);
          #pragma unroll
          for (int tt = 0; tt < 4; ++tt){
            short8 bf = *reinterpret_cast<const short8*>(wBw + (size_t)((tt*2 + kb))*512 + (size_t)lane*8);
            acc[tt] = __builtin_amdgcn_mfma_f32_16x16x32_bf16(af, bf, acc[tt], 0, 0, 0);
          }
        }
      } else {
        gate_gemm<27>(Ap, wB, t, lane, wave, acc);
      }
      {
        const int c = lane & 15, rb = wave*16 + ((lane>>4)<<2);
        #pragma unroll
        for (int tt = 0; tt < 4; ++tt)
          #pragma unroll
          for (int rr2 = 0; rr2 < 4; ++rr2)
            ldsg[rb+rr2][tt*16 + c] = acc[tt][rr2];
      }
      __syncthreads();
      for (int cell = tid; cell < 1024; cell += 256){
        int jj = cell >> 6, b = cell & 63;
        int j = s*16 + jj, tt = jj >> 2, jo = jj & 3;
        float gi = ldsg[b][tt*16 +      jo] + bsum[jj*4 + 0];
        float gf = ldsg[b][tt*16 +  4 + jo] + bsum[jj*4 + 1];
        float gg = ldsg[b][tt*16 +  8 + jo] + bsum[jj*4 + 2];
        float go = ldsg[b][tt*16 + 12 + jo] + bsum[jj*4 + 3];
        float cp = clds[jj][b];
        float cn = sigm(gf)*cp + sigm(gi)*tanh_f(gg);
        float hh = sigm(go)*tanh_f(cn);
        clds[jj][b] = cn;
        u16 hb = f2bf(hh);
        yr[((size_t)t*64 + b)*400 + j] = hb;
        if (grp == 0){
          p.A1[aidx(t,b,j,27)] = hb;
          if (t < 511) p.A0[aidx(t+1,b,3+j,13)] = hb;
          hsh[jj][b] = hh;
        } else if (grp == 1){
          p.A2[aidx(t,b,j,27)] = hb;
          if (t < 511) p.A1[aidx(t+1,b,463+j,27)] = hb;
        } else {
          if (t < 511) p.A2[aidx(t+1,b,463+j,27)] = hb;
        }
        if (t == 511){ p.out[ohh + b*400 + j] = hh; p.out[occ + b*400 + j] = cn; }
      }
      if (grp == 0){
        __syncthreads();
        float* od = p.obuf + (size_t)(r%3)*9600 + (size_t)(s%5)*1920;
        for (int cell = tid; cell < 1920; cell += 256){
          int b = cell & 63, n = cell >> 6;
          float sum = 0.f;
          #pragma unroll
          for (int jj = 0; jj < 16; ++jj)
            sum += hsh[jj][b] * wwin_l[n][jj];
          atomicAdd(&od[n*64 + b], sum);
        }
      }
    }
    // rotate-zero the 5-bank o-slot round r+1 writes; spread over 25 grp2 WGs
    if (wg >= 50 && r <= 510){
      float* oz = p.obuf + (size_t)((r+1)%3)*9600 + (size_t)(wg-50)*384;
      for (int cell = tid; cell < 384; cell += 256)
        __hip_atomic_store(&oz[cell], 0.f, __ATOMIC_RELAXED, __HIP_MEMORY_SCOPE_AGENT);
    }
    if (r < 514) gsync(p.bar, wg, (unsigned)(r+1));
  }
}

// ---------------- output heads ----------------
__global__ __launch_bounds__(256) void kproj(P p){
  const int t = blockIdx.x >> 3, ns = blockIdx.x & 7;
  const int tid = threadIdx.x, lane = tid & 63, wave = tid >> 6;
  const int m = lane & 15, q = lane >> 4;
  float4v acc = {0.f,0.f,0.f,0.f};
  const size_t rowA = (size_t)t*64 + wave*16 + m;
  const u16* Bb = p.BP + ((size_t)ns*38)*512 + (size_t)lane*8;
  for (int kb = 0; kb < 38; ++kb){
    int k0 = kb*32 + q*8;
    const u16* src; int off;
    if (k0 < 400){ src = p.y0; off = k0; }
    else if (k0 < 800){ src = p.y1; off = k0 - 400; }
    else if (k0 < 1200){ src = p.y2; off = k0 - 800; }
    else { src = p.y0; off = 0; }     // B rows are zero for k>=1200
    short8 af = *reinterpret_cast<const short8*>(src + rowA*400 + off);
    short8 bf = *reinterpret_cast<const short8*>(Bb + (size_t)kb*512);
    acc = __builtin_amdgcn_mfma_f32_16x16x32_bf16(af, bf, acc, 0, 0, 0);
  }
  const int j = ns*16 + (lane & 15);
  const int bo = wave*16 + q*4;
  #pragma unroll
  for (int rr = 0; rr < 4; ++rr){
    float v = acc[rr];
    size_t ro = (size_t)t*64 + bo + rr;
    if (j < 40)        p.out[O_MEANS + ro*40 + j]        = v + p.bmu[j];
    else if (j < 80)   p.out[O_LS    + ro*40 + (j-40)]   = v + p.bls[j-40];
    else if (j < 100)  p.out[O_RHO   + ro*20 + (j-80)]   = tanhf(v + p.brho[j-80]);
    else if (j < 120)  p.out[O_PI    + ro*20 + (j-100)]  = v + p.bpi[j-100];
    else if (j == 120) p.out[O_EOS   + ro]               = v + p.beos[0];
  }
}

// ---------------- host ----------------
extern "C" void kernel_launch(void* const* d_in, const int* in_sizes, int n_in,
                              void* d_out, int out_size, void* d_ws, size_t ws_size,
                              hipStream_t stream){
  P p;
  p.strokes = (const float*)d_in[0];
  p.text    = (const int*)  d_in[1];
  p.tlen    = (const int*)  d_in[2];
  p.h0h = (const float*)d_in[3];  p.h0c = (const float*)d_in[4];
  p.h1h = (const float*)d_in[5];  p.h1c = (const float*)d_in[6];
  p.h2h = (const float*)d_in[7];  p.h2c = (const float*)d_in[8];
  p.pw  = (const float*)d_in[9];  p.pk  = (const float*)d_in[10];
  const float* Wih0 = (const float*)d_in[11]; const float* Whh0 = (const float*)d_in[12];
  p.bih0 = (const float*)d_in[13]; p.bhh0 = (const float*)d_in[14];
  const float* Wih1 = (const float*)d_in[15]; const float* Whh1 = (const float*)d_in[16];
  p.bih1 = (const float*)d_in[17]; p.bhh1 = (const float*)d_in[18];
  const float* Wih2 = (const float*)d_in[19]; const float* Whh2 = (const float*)d_in[20];
  p.bih2 = (const float*)d_in[21]; p.bhh2 = (const float*)d_in[22];
  p.Wwin = (const float*)d_in[23]; p.bwin = (const float*)d_in[24];
  const float* Wmu  = (const float*)d_in[25]; p.bmu  = (const float*)d_in[26];
  const float* Wls  = (const float*)d_in[27]; p.bls  = (const float*)d_in[28];
  const float* Wrho = (const float*)d_in[29]; p.brho = (const float*)d_in[30];
  const float* Wpi  = (const float*)d_in[31]; p.bpi  = (const float*)d_in[32];
  const float* Weos = (const float*)d_in[33]; p.beos = (const float*)d_in[34];
  p.out = (float*)d_out;

  char* w = (char*)d_ws; size_t off = 0;
  auto alloc = [&](size_t bytes)->void*{ void* r = w + off; off += (bytes + 511) & ~(size_t)511; return r; };
  p.B0  = (u16*)alloc((size_t)25*4*13*512*2);
  p.B1  = (u16*)alloc((size_t)25*4*27*512*2);
  p.B2  = (u16*)alloc((size_t)25*4*27*512*2);
  p.Bw0 = (u16*)alloc((size_t)25*4*2*512*2);
  p.BP  = (u16*)alloc((size_t)8*38*512*2);
  p.A0  = (u16*)alloc((size_t)512*4*13*512*2);
  p.A1  = (u16*)alloc((size_t)512*4*27*512*2);
  p.A2  = (u16*)alloc((size_t)512*4*27*512*2);
  p.y0  = (u16*)alloc((size_t)512*64*400*2);
  p.y1  = (u16*)alloc((size_t)512*64*400*2);
  p.y2  = (u16*)alloc((size_t)512*64*400*2);
  p.obuf= (float*)alloc((size_t)3*9600*4);
  p.bar = (unsigned*)alloc((size_t)2432*4);

  kpackB<<<dim3(2600), dim3(256), 0, stream>>>(Wih0, Whh0, p.B0, 13, 3,   63,  25*4*13*512);
  kpackB<<<dim3(5400), dim3(256), 0, stream>>>(Wih1, Whh1, p.B1, 27, 463, 463, 25*4*27*512);
  kpackB<<<dim3(5400), dim3(256), 0, stream>>>(Wih2, Whh2, p.B2, 27, 463, 463, 25*4*27*512);
  kpackBw<<<dim3(400), dim3(256), 0, stream>>>(Wih0, p.Bw0);
  kpackBP<<<dim3(608), dim3(256), 0, stream>>>(Wmu, Wls, Wrho, Wpi, Weos, p.BP);
  kfillA<<<dim3(4096), dim3(256), 0, stream>>>(p);
  kinit<<<dim3(422), dim3(256), 0, stream>>>(p);

  // plain launch: custom barrier needs no cooperative API; 75 WGs are
  // co-resident by construction (1 WG/CU min occupancy, 256 CUs).
  kmain<<<dim3(75), dim3(256), 0, stream>>>(p);

  kproj<<<dim3(4096), dim3(256), 0, stream>>>(p);
}

// Round 9
// 8787.386 us; speedup vs baseline: 4.7096x; 1.0390x over previous
//
#include <hip/hip_runtime.h>

typedef unsigned short u16;
typedef __attribute__((ext_vector_type(8))) short short8;   // 8 x bf16
typedef __attribute__((ext_vector_type(4))) float float4v;  // MFMA acc

// ---- output offsets (floats) ----
#define O_MEANS 0
#define O_LS    1310720
#define O_RHO   2621440
#define O_PI    3276800
#define O_EOS   3932160
#define O_H0H   3964928
#define O_H0C   3990528
#define O_H1H   4016128
#define O_H1C   4041728
#define O_H2H   4067328
#define O_H2C   4092928
#define O_PW    4118528
#define O_PK    4122368
#define O_AL    4123008

// bar: 3 groups x 1024 u32; group g: flags at [g*1024 + i*32] (i=0..24, 128B apart),
// generation word at [g*1024 + 800].
#define BARG(g)   ((g)*1024)
#define GENOFF    800

struct P {
  const float *strokes; const int *text; const int *tlen;
  const float *h0h,*h0c,*h1h,*h1c,*h2h,*h2c,*pw,*pk;
  const float *bih0,*bhh0,*bih1,*bhh1,*bih2,*bhh2;
  const float *Wwin,*bwin;
  const float *bmu,*bls,*brho,*bpi,*beos;
  u16 *B0,*B1,*B2,*Bw0,*BP;     // fragment-packed weights
  u16 *A0,*A1,*A2;              // fragment-packed activations per step
  u16 *y0,*y1,*y2;              // bf16 row-major hidden histories [T][64][400]
  float *obuf;                  // 3 rounds x 5 banks x [30][64] o-partials (atomic-only)
  unsigned *bar;                // 3 independent group barriers
  float *out;
};

__device__ __forceinline__ u16 f2bf(float f){
  unsigned int x = __float_as_uint(f);
  unsigned int r = x + 0x7FFFu + ((x >> 16) & 1u);
  return (u16)(r >> 16);
}
// A-pack element (t, batch b, k) for a layer with KB k-blocks.
// block = (t*4 + b/16)*KB + k/32 ; inside: lane=((k>>3)&3)*16+(b&15), elem k&7
__device__ __forceinline__ size_t aidx(int t, int b, int k, int KB){
  return ((size_t)((t*4 + (b>>4))*KB + (k>>5)))*512
       + (size_t)(((((k>>3)&3)*16) + (b&15))*8 + (k&7));
}
__device__ __forceinline__ float sigm(float x){ return 1.f/(1.f+__expf(-x)); }
__device__ __forceinline__ float tanh_f(float x){ return 2.f/(1.f+__expf(-2.f*x)) - 1.f; }

// ---------------- weight packing ----------------
__global__ void kpackB(const float* __restrict__ Wih, const float* __restrict__ Whh,
                       u16* __restrict__ dst, int KB, int kx, int stride, int total){
  int tid = blockIdx.x*256 + threadIdx.x;
  if (tid >= total) return;
  int e = tid & 511, blk = tid >> 9;
  int kb = blk % KB, tile = (blk / KB) & 3, s = blk / (KB*4);
  int lane = e >> 3, j = e & 7;
  int q = lane >> 4, n = lane & 15;
  int k = kb*32 + q*8 + j;
  int col = s*16 + tile*4 + (n&3);
  int g = (n>>2)*400 + col;
  float v = 0.f;
  if (k < kx) v = Wih[(size_t)g*stride + k];
  else if (k < kx + 400) v = Whh[(size_t)g*400 + (k - kx)];
  dst[tid] = f2bf(v);
}

// inline-w weights for L0: [25][4][2][512], from Wih0 cols 3..62
__global__ void kpackBw(const float* __restrict__ Wih0, u16* __restrict__ dst){
  int tid = blockIdx.x*256 + threadIdx.x;
  if (tid >= 25*4*2*512) return;
  int e = tid & 511, blk = tid >> 9;
  int kb = blk & 1, tile = (blk>>1) & 3, s = blk >> 3;
  int lane = e >> 3, j = e & 7;
  int q = lane >> 4, n = lane & 15;
  int k = kb*32 + q*8 + j;
  int col = s*16 + tile*4 + (n&3);
  int g = (n>>2)*400 + col;
  dst[tid] = (k < 60) ? f2bf(Wih0[(size_t)g*63 + 3 + k]) : (u16)0;
}

// projection weights: cols 0..39 mu, 40..79 ls, 80..99 rho, 100..119 pi, 120 eos
__global__ void kpackBP(const float* __restrict__ Wmu, const float* __restrict__ Wls,
                        const float* __restrict__ Wrho, const float* __restrict__ Wpi,
                        const float* __restrict__ Weos, u16* __restrict__ dst){
  int tid = blockIdx.x*256 + threadIdx.x;
  if (tid >= 8*38*512) return;
  int e = tid & 511, blk = tid >> 9;
  int lane = e >> 3, j = e & 7;
  int ns = blk / 38, kb = blk % 38;
  int q = lane >> 4, n = lane & 15;
  int k = kb*32 + q*8 + j;
  int col = ns*16 + n;
  float v = 0.f;
  if (k < 1200){
    if (col < 40)       v = Wmu[(size_t)col*1200 + k];
    else if (col < 80)  v = Wls[(size_t)(col-40)*1200 + k];
    else if (col < 100) v = Wrho[(size_t)(col-80)*1200 + k];
    else if (col < 120) v = Wpi[(size_t)(col-100)*1200 + k];
    else if (col == 120) v = Weos[k];
  }
  dst[tid] = f2bf(v);
}

// strokes rows + zero pads for all t (ws is 0xAA-poisoned every run)
__global__ void kfillA(P p){
  int tid = blockIdx.x*256 + threadIdx.x;
  if (tid >= 512*64*32) return;
  int it = tid & 31; int rr = tid >> 5; int b = rr & 63; int t = rr >> 6;
  const float* sx = p.strokes + ((size_t)t*64 + b)*3;
  if (it < 3)        p.A0[aidx(t,b,it,13)] = f2bf(sx[it]);
  else if (it < 16)  p.A0[aidx(t,b,400+it,13)] = 0;          // pads 403..415
  else if (it < 19)  p.A1[aidx(t,b,460+(it-16),27)] = f2bf(sx[it-16]);
  else if (it == 19) p.A1[aidx(t,b,863,27)] = 0;
  else if (it < 23)  p.A2[aidx(t,b,460+(it-20),27)] = f2bf(sx[it-20]);
  else if (it == 23) p.A2[aidx(t,b,863,27)] = 0;
}

// initial states + obuf/barrier zero
__global__ void kinit(P p){
  int tid = blockIdx.x*256 + threadIdx.x;
  if (tid < 25600){ int b=tid/400, j=tid%400; p.A0[aidx(0,b,3+j,13)] = f2bf(p.h0h[tid]); }
  else if (tid < 51200){ int i=tid-25600; int b=i/400, j=i%400; p.A1[aidx(0,b,463+j,27)] = f2bf(p.h1h[i]); }
  else if (tid < 76800){ int i=tid-51200; int b=i/400, j=i%400; p.A2[aidx(0,b,463+j,27)] = f2bf(p.h2h[i]); }
  else if (tid < 105600){ p.obuf[tid-76800] = 0.f; }
  else if (tid < 108672){ p.bar[tid-105600] = 0u; }
}

// ---------------- per-group 25-WG barrier ----------------
// R8 mechanics scaled to one group: RELEASE arrival (flushes this WG's dirty
// cross-WG lines to IC), group leader (sidx==0) polls the 25 flags with wave0
// lanes 0..24 (single wave -> loop reconvergence proves all seen, no wave race),
// then lane 0 publishes the group generation. No acquire fences needed:
// cross-WG plain-store data is write-once/read-once at fresh addresses; the one
// recycled object (obuf) is atomic-only and group-local.
__device__ __forceinline__ void gsync25(unsigned* barg, int sidx, unsigned target){
  __syncthreads();
  const int tid = threadIdx.x;
  if (sidx == 0){
    if (tid == 0)
      __hip_atomic_store(&barg[0], target, __ATOMIC_RELEASE, __HIP_MEMORY_SCOPE_AGENT);
    if (tid < 25){
      long c = 0;
      while (__hip_atomic_load(&barg[tid*32], __ATOMIC_RELAXED, __HIP_MEMORY_SCOPE_AGENT) < target){
        __builtin_amdgcn_s_sleep(1);
        if (++c > (1L<<25)) break;   // failsafe: wrong answer, never a hang
      }
      if (tid == 0)   // wave0 reconverged => all 25 flags observed
        __hip_atomic_store(&barg[GENOFF], target, __ATOMIC_RELAXED, __HIP_MEMORY_SCOPE_AGENT);
    }
  } else {
    if (tid == 0){
      __hip_atomic_store(&barg[sidx*32], target, __ATOMIC_RELEASE, __HIP_MEMORY_SCOPE_AGENT);
      long c = 0;
      while (__hip_atomic_load(&barg[GENOFF], __ATOMIC_RELAXED, __HIP_MEMORY_SCOPE_AGENT) < target){
        __builtin_amdgcn_s_sleep(1);
        if (++c > (1L<<25)) break;
      }
    }
  }
  __syncthreads();
}

// wait for another group's generation (read-only, expected pre-satisfied by lag)
__device__ __forceinline__ void waitgen(const unsigned* gw, unsigned target){
  if (threadIdx.x == 0){
    long c = 0;
    while (__hip_atomic_load(gw, __ATOMIC_RELAXED, __HIP_MEMORY_SCOPE_AGENT) < target){
      __builtin_amdgcn_s_sleep(1);
      if (++c > (1L<<25)) break;
    }
  }
  __syncthreads();
}

// ---------------- gate GEMM: A from global (IC), B from LDS ----------------
template<int KB>
__device__ __forceinline__ void gate_gemm(const u16* __restrict__ Ap, const u16* wBl,
                                          int t, int lane, int wave, float4v* acc){
  const u16* Ab = Ap + ((size_t)(t*4 + wave)*KB)*512 + (size_t)lane*8;
  const u16* Bb = wBl + lane*8;
  #pragma unroll
  for (int kb = 0; kb < KB; ++kb){
    short8 af = *reinterpret_cast<const short8*>(Ab + (size_t)kb*512);
    #pragma unroll
    for (int tt = 0; tt < 4; ++tt){
      short8 bf = *reinterpret_cast<const short8*>(Bb + (size_t)(tt*KB + kb)*512);
      acc[tt] = __builtin_amdgcn_mfma_f32_16x16x32_bf16(af, bf, acc[tt], 0, 0, 0);
    }
  }
}

// ---------------- main persistent kernel: 3 decoupled groups ----------------
// grp0 (wg 0..24):  L0 at t=r + window finalize w(r-1) + o-partials + obuf zero
// grp1 (wg 25..49): L1 at t=r-2; waits g0 >= r
// grp2 (wg 50..74): L2 at t=r-3; waits g1 >= r (g0 transitively)
__global__ __launch_bounds__(256, 1) void kmain(P p){
  const int wg = blockIdx.x, tid = threadIdx.x;
  const int lane = tid & 63, wave = tid >> 6;
  const int grp = (wg < 25) ? 0 : (wg < 50 ? 1 : 2);
  const int s = wg - grp*25;
  const int lag = (grp == 0) ? 0 : (grp + 1);   // 0,2,3

  __shared__ u16  wB[55296];         // 110592 B weight slice (+ grp0 overlay)
  __shared__ float ldsg[64][65];     // gate tile [b][4 tiles *16 cols]
  __shared__ float clds[16][64];     // persistent cell state [jj][b]
  __shared__ float bsum[64];         // bias sums [jj*4+gate], this slice

  // grp0 overlays in wB[30720..55295] (49152 B available, 46328 used)
  u16* wBw = wB + 26624;                                   // 8 KB inline-w weights
  char* exb = (char*)(wB + 30720);
  float (*hsh)[64]  = (float (*)[64])(exb);                //  4096 B  h0 stage
  float (*wacc)[64] = (float (*)[64])(exb + 4096);         // 15360 B  w accum
  u16   (*wbf)[80]  = (u16   (*)[80])(exb + 19456);        // 10240 B  w A-operand
  float (*klds)[10] = (float (*)[10])(exb + 29696);        //  2560 B  kappa
  float (*ash)[10]  = (float (*)[10])(exb + 32256);
  float (*bsh)[10]  = (float (*)[10])(exb + 34816);
  float (*ksh)[10]  = (float (*)[10])(exb + 37376);        // end 39936
  float (*wwin_l)[16] = (float (*)[16])(exb + 39936);      //  1920 B Wwin slice
  unsigned char* text_l = (unsigned char*)(exb + 41856);   //  4096 B text (u8)
  int*   tlen_l = (int*)(exb + 45952);                     //   256 B
  float* bwin_l = (float*)(exb + 46208);                   //   120 B, end 46328

  const u16 *Ap; u16 *yr;
  const float *bi, *bh, *cin; int ohh, occ;
  if (grp == 0){ Ap=p.A0; yr=p.y0; bi=p.bih0; bh=p.bhh0; cin=p.h0c; ohh=O_H0H; occ=O_H0C; }
  else if (grp == 1){ Ap=p.A1; yr=p.y1; bi=p.bih1; bh=p.bhh1; cin=p.h1c; ohh=O_H1H; occ=O_H1C; }
  else { Ap=p.A2; yr=p.y2; bi=p.bih2; bh=p.bhh2; cin=p.h2c; ohh=O_H2H; occ=O_H2C; }
  unsigned* mybar = p.bar + BARG(grp);

  // ---- stage weight slice into LDS (once) ----
  {
    const u16* gsrc; int cnt;
    if (grp == 0){ gsrc = p.B0 + (size_t)s*26624; cnt = 26624; }
    else if (grp == 1){ gsrc = p.B1 + (size_t)s*55296; cnt = 55296; }
    else { gsrc = p.B2 + (size_t)s*55296; cnt = 55296; }
    for (int i = tid*8; i < cnt; i += 2048)
      *reinterpret_cast<short8*>(&wB[i]) = *reinterpret_cast<const short8*>(gsrc + i);
    if (grp == 0){
      const u16* gw = p.Bw0 + (size_t)s*4096;
      for (int i = tid*8; i < 4096; i += 2048)
        *reinterpret_cast<short8*>(wBw + i) = *reinterpret_cast<const short8*>(gw + i);
    }
  }

  for (int cell = tid; cell < 1024; cell += 256){
    int jj = cell >> 6, b = cell & 63;
    clds[jj][b] = cin[b*400 + s*16 + jj];
  }
  if (tid < 64){
    int jj = tid >> 2, gg = tid & 3;
    bsum[tid] = bi[gg*400 + s*16 + jj] + bh[gg*400 + s*16 + jj];
  }
  if (grp == 0){
    for (int cell = tid; cell < 640; cell += 256) klds[cell/10][cell%10] = p.pk[cell];
    for (int cell = tid; cell < 64*80; cell += 256){
      int b = cell/80, k = cell%80;
      wbf[b][k] = (k < 60) ? f2bf(p.pw[b*60 + k]) : (u16)0;
    }
    for (int cell = tid; cell < 480; cell += 256)
      wwin_l[cell>>4][cell&15] = p.Wwin[(cell>>4)*400 + s*16 + (cell&15)];
    for (int cell = tid; cell < 4096; cell += 256)
      text_l[cell] = (unsigned char)p.text[cell];
    if (tid < 64) tlen_l[tid] = p.tlen[tid];
    if (tid < 30) bwin_l[tid] = p.bwin[tid];
  }
  __syncthreads();

  for (int r = 0; r < 515; ++r){
    const int t = r - lag;

    // ---- cross-group ordering (expected pre-satisfied by pipeline lag) ----
    if (grp == 1 && r >= 2 && r <= 513) waitgen(p.bar + BARG(0) + GENOFF, (unsigned)r);
    if (grp == 2 && r >= 3 && r <= 514) waitgen(p.bar + BARG(1) + GENOFF, (unsigned)r);

    // ---- grp0: hoist obuf bank loads (5-bank, /5 contention) then A0 frags ----
    float ovs[8][5];
    if (grp == 0 && r >= 1 && r <= 512){
      const float* ob = p.obuf + (size_t)((r-1)%3)*9600;
      #pragma unroll
      for (int i = 0; i < 8; ++i){
        int cell = tid + i*256;
        if (cell < 1920){
          #pragma unroll
          for (int bk = 0; bk < 5; ++bk)
            ovs[i][bk] = __hip_atomic_load(&ob[bk*1920 + cell], __ATOMIC_RELAXED, __HIP_MEMORY_SCOPE_AGENT);
        }
      }
    }
    short8 a0r[13];
    if (grp == 0 && t < 512){
      const u16* Ab = p.A0 + ((size_t)(t*4 + wave)*13)*512 + (size_t)lane*8;
      #pragma unroll
      for (int kb = 0; kb < 13; ++kb)
        a0r[kb] = *reinterpret_cast<const short8*>(Ab + (size_t)kb*512);
    }

    // ---- window finalize for t = r-1 (replicated across the 25 L0 WGs) ----
    if (grp == 0 && r >= 1 && r <= 512){
      const int tw = r - 1;
      #pragma unroll
      for (int i = 0; i < 8; ++i){
        int cell = tid + i*256;
        if (cell < 1920){
          int b = cell & 63, n = cell >> 6;
          float o = ovs[i][0]+ovs[i][1]+ovs[i][2]+ovs[i][3]+ovs[i][4] + bwin_l[n];
          if (n < 10) ash[b][n] = __expf(o);
          else if (n < 20) bsh[b][n-10] = __expf(o);
          else { float kn = klds[b][n-20] + 0.05f*__expf(o); klds[b][n-20] = kn; ksh[b][n-20] = kn; }
        }
      }
      for (int cell = tid; cell < 3840; cell += 256) ((float*)wacc)[cell] = 0.f;
      __syncthreads();
      for (int cell = tid; cell < 4096; cell += 256){
        int b = cell >> 6, u = cell & 63;
        float phi = 0.f;
        if (u < tlen_l[b]){
          #pragma unroll
          for (int n = 0; n < 10; ++n){
            float d = ksh[b][n] - (float)u;
            phi += ash[b][n]*__expf(-bsh[b][n]*d*d);
          }
          atomicAdd(&wacc[text_l[b*64 + u]][b], phi);
        }
        if (wg == 4) p.out[O_AL + ((size_t)tw*64 + b)*64 + u] = phi;
      }
      __syncthreads();
      for (int cell = tid; cell < 3840; cell += 256){
        int b = cell & 63, l = cell >> 6;
        u16 wv = f2bf(wacc[l][b]);
        wbf[b][l] = wv;
        if (wg == 1) p.A1[aidx(tw,b,400+l,27)] = wv;
        if (wg == 2) p.A2[aidx(tw,b,400+l,27)] = wv;
        if (wg == 0 && tw == 511) p.out[O_PW + b*60 + l] = wacc[l][b];
      }
      if (wg == 0 && tw == 511)
        for (int cell = tid; cell < 640; cell += 256) p.out[O_PK + cell] = klds[cell/10][cell%10];
      __syncthreads();
    }

    // ---- gate GEMM + LSTM pointwise ----
    if (t >= 0 && t < 512){
      float4v acc[4] = {{0.f,0.f,0.f,0.f},{0.f,0.f,0.f,0.f},{0.f,0.f,0.f,0.f},{0.f,0.f,0.f,0.f}};
      if (grp == 0){
        #pragma unroll
        for (int kb = 0; kb < 13; ++kb){
          #pragma unroll
          for (int tt = 0; tt < 4; ++tt){
            short8 bf = *reinterpret_cast<const short8*>(wB + (size_t)(tt*13 + kb)*512 + (size_t)lane*8);
            acc[tt] = __builtin_amdgcn_mfma_f32_16x16x32_bf16(a0r[kb], bf, acc[tt], 0, 0, 0);
          }
        }
        const int m = lane & 15, q = (lane >> 4) & 3;
        #pragma unroll
        for (int kb = 0; kb < 2; ++kb){
          short8 af = *reinterpret_cast<const short8*>(&wbf[wave*16 + m][kb*32 + q*8]);
          #pragma unroll
          for (int tt = 0; tt < 4; ++tt){
            short8 bf = *reinterpret_cast<const short8*>(wBw + (size_t)((tt*2 + kb))*512 + (size_t)lane*8);
            acc[tt] = __builtin_amdgcn_mfma_f32_16x16x32_bf16(af, bf, acc[tt], 0, 0, 0);
          }
        }
      } else {
        gate_gemm<27>(Ap, wB, t, lane, wave, acc);
      }
      {
        const int c = lane & 15, rb = wave*16 + ((lane>>4)<<2);
        #pragma unroll
        for (int tt = 0; tt < 4; ++tt)
          #pragma unroll
          for (int rr2 = 0; rr2 < 4; ++rr2)
            ldsg[rb+rr2][tt*16 + c] = acc[tt][rr2];
      }
      __syncthreads();
      for (int cell = tid; cell < 1024; cell += 256){
        int jj = cell >> 6, b = cell & 63;
        int j = s*16 + jj, tt = jj >> 2, jo = jj & 3;
        float gi = ldsg[b][tt*16 +      jo] + bsum[jj*4 + 0];
        float gf = ldsg[b][tt*16 +  4 + jo] + bsum[jj*4 + 1];
        float gg = ldsg[b][tt*16 +  8 + jo] + bsum[jj*4 + 2];
        float go = ldsg[b][tt*16 + 12 + jo] + bsum[jj*4 + 3];
        float cp = clds[jj][b];
        float cn = sigm(gf)*cp + sigm(gi)*tanh_f(gg);
        float hh = sigm(go)*tanh_f(cn);
        clds[jj][b] = cn;
        u16 hb = f2bf(hh);
        yr[((size_t)t*64 + b)*400 + j] = hb;
        if (grp == 0){
          p.A1[aidx(t,b,j,27)] = hb;
          if (t < 511) p.A0[aidx(t+1,b,3+j,13)] = hb;
          hsh[jj][b] = hh;
        } else if (grp == 1){
          p.A2[aidx(t,b,j,27)] = hb;
          if (t < 511) p.A1[aidx(t+1,b,463+j,27)] = hb;
        } else {
          if (t < 511) p.A2[aidx(t+1,b,463+j,27)] = hb;
        }
        if (t == 511){ p.out[ohh + b*400 + j] = hh; p.out[occ + b*400 + j] = cn; }
      }
      if (grp == 0){
        __syncthreads();
        float* od = p.obuf + (size_t)(r%3)*9600 + (size_t)(s%5)*1920;
        for (int cell = tid; cell < 1920; cell += 256){
          int b = cell & 63, n = cell >> 6;
          float sum = 0.f;
          #pragma unroll
          for (int jj = 0; jj < 16; ++jj)
            sum += hsh[jj][b] * wwin_l[n][jj];
          atomicAdd(&od[n*64 + b], sum);
        }
      }
    }
    // grp0 zeroes its own next-next o-slot (consumed at round r-1 -> safe), spread over 25 WGs
    if (grp == 0 && r <= 510){
      float* oz = p.obuf + (size_t)((r+1)%3)*9600 + (size_t)s*384;
      for (int cell = tid; cell < 384; cell += 256)
        __hip_atomic_store(&oz[cell], 0.f, __ATOMIC_RELAXED, __HIP_MEMORY_SCOPE_AGENT);
    }
    if (r < 514) gsync25(mybar, s, (unsigned)(r+1));
  }
}

// ---------------- output heads ----------------
__global__ __launch_bounds__(256) void kproj(P p){
  const int t = blockIdx.x >> 3, ns = blockIdx.x & 7;
  const int tid = threadIdx.x, lane = tid & 63, wave = tid >> 6;
  const int m = lane & 15, q = lane >> 4;
  float4v acc = {0.f,0.f,0.f,0.f};
  const size_t rowA = (size_t)t*64 + wave*16 + m;
  const u16* Bb = p.BP + ((size_t)ns*38)*512 + (size_t)lane*8;
  for (int kb = 0; kb < 38; ++kb){
    int k0 = kb*32 + q*8;
    const u16* src; int off;
    if (k0 < 400){ src = p.y0; off = k0; }
    else if (k0 < 800){ src = p.y1; off = k0 - 400; }
    else if (k0 < 1200){ src = p.y2; off = k0 - 800; }
    else { src = p.y0; off = 0; }     // B rows are zero for k>=1200
    short8 af = *reinterpret_cast<const short8*>(src + rowA*400 + off);
    short8 bf = *reinterpret_cast<const short8*>(Bb + (size_t)kb*512);
    acc = __builtin_amdgcn_mfma_f32_16x16x32_bf16(af, bf, acc, 0, 0, 0);
  }
  const int j = ns*16 + (lane & 15);
  const int bo = wave*16 + q*4;
  #pragma unroll
  for (int rr = 0; rr < 4; ++rr){
    float v = acc[rr];
    size_t ro = (size_t)t*64 + bo + rr;
    if (j < 40)        p.out[O_MEANS + ro*40 + j]        = v + p.bmu[j];
    else if (j < 80)   p.out[O_LS    + ro*40 + (j-40)]   = v + p.bls[j-40];
    else if (j < 100)  p.out[O_RHO   + ro*20 + (j-80)]   = tanhf(v + p.brho[j-80]);
    else if (j < 120)  p.out[O_PI    + ro*20 + (j-100)]  = v + p.bpi[j-100];
    else if (j == 120) p.out[O_EOS   + ro]               = v + p.beos[0];
  }
}

// ---------------- host ----------------
extern "C" void kernel_launch(void* const* d_in, const int* in_sizes, int n_in,
                              void* d_out, int out_size, void* d_ws, size_t ws_size,
                              hipStream_t stream){
  P p;
  p.strokes = (const float*)d_in[0];
  p.text    = (const int*)  d_in[1];
  p.tlen    = (const int*)  d_in[2];
  p.h0h = (const float*)d_in[3];  p.h0c = (const float*)d_in[4];
  p.h1h = (const float*)d_in[5];  p.h1c = (const float*)d_in[6];
  p.h2h = (const float*)d_in[7];  p.h2c = (const float*)d_in[8];
  p.pw  = (const float*)d_in[9];  p.pk  = (const float*)d_in[10];
  const float* Wih0 = (const float*)d_in[11]; const float* Whh0 = (const float*)d_in[12];
  p.bih0 = (const float*)d_in[13]; p.bhh0 = (const float*)d_in[14];
  const float* Wih1 = (const float*)d_in[15]; const float* Whh1 = (const float*)d_in[16];
  p.bih1 = (const float*)d_in[17]; p.bhh1 = (const float*)d_in[18];
  const float* Wih2 = (const float*)d_in[19]; const float* Whh2 = (const float*)d_in[20];
  p.bih2 = (const float*)d_in[21]; p.bhh2 = (const float*)d_in[22];
  p.Wwin = (const float*)d_in[23]; p.bwin = (const float*)d_in[24];
  const float* Wmu  = (const float*)d_in[25]; p.bmu  = (const float*)d_in[26];
  const float* Wls  = (const float*)d_in[27]; p.bls  = (const float*)d_in[28];
  const float* Wrho = (const float*)d_in[29]; p.brho = (const float*)d_in[30];
  const float* Wpi  = (const float*)d_in[31]; p.bpi  = (const float*)d_in[32];
  const float* Weos = (const float*)d_in[33]; p.beos = (const float*)d_in[34];
  p.out = (float*)d_out;

  char* w = (char*)d_ws; size_t off = 0;
  auto alloc = [&](size_t bytes)->void*{ void* r = w + off; off += (bytes + 511) & ~(size_t)511; return r; };
  p.B0  = (u16*)alloc((size_t)25*4*13*512*2);
  p.B1  = (u16*)alloc((size_t)25*4*27*512*2);
  p.B2  = (u16*)alloc((size_t)25*4*27*512*2);
  p.Bw0 = (u16*)alloc((size_t)25*4*2*512*2);
  p.BP  = (u16*)alloc((size_t)8*38*512*2);
  p.A0  = (u16*)alloc((size_t)512*4*13*512*2);
  p.A1  = (u16*)alloc((size_t)512*4*27*512*2);
  p.A2  = (u16*)alloc((size_t)512*4*27*512*2);
  p.y0  = (u16*)alloc((size_t)512*64*400*2);
  p.y1  = (u16*)alloc((size_t)512*64*400*2);
  p.y2  = (u16*)alloc((size_t)512*64*400*2);
  p.obuf= (float*)alloc((size_t)3*9600*4);
  p.bar = (unsigned*)alloc((size_t)3072*4);

  kpackB<<<dim3(2600), dim3(256), 0, stream>>>(Wih0, Whh0, p.B0, 13, 3,   63,  25*4*13*512);
  kpackB<<<dim3(5400), dim3(256), 0, stream>>>(Wih1, Whh1, p.B1, 27, 463, 463, 25*4*27*512);
  kpackB<<<dim3(5400), dim3(256), 0, stream>>>(Wih2, Whh2, p.B2, 27, 463, 463, 25*4*27*512);
  kpackBw<<<dim3(400), dim3(256), 0, stream>>>(Wih0, p.Bw0);
  kpackBP<<<dim3(608), dim3(256), 0, stream>>>(Wmu, Wls, Wrho, Wpi, Weos, p.BP);
  kfillA<<<dim3(4096), dim3(256), 0, stream>>>(p);
  kinit<<<dim3(425), dim3(256), 0, stream>>>(p);

  // plain launch: custom barriers need no cooperative API; 75 WGs are
  // co-resident by construction (1 WG/CU min occupancy, 256 CUs).
  kmain<<<dim3(75), dim3(256), 0, stream>>>(p);

  kproj<<<dim3(4096), dim3(256), 0, stream>>>(p);
}